// Round 1
// baseline (6510.738 us; speedup 1.0000x reference)
//
#include <hip/hip_runtime.h>
#include <math.h>

#define BSZ 4
#define CCH 512
#define NPIX 4096
#define NGRP 8
#define CPG 64
#define EPSV 1e-5f
#define SCALE 0.044194173824159216f  // 512^-0.5

// ---------------------------------------------------------------- GroupNorm
__global__ __launch_bounds__(256) void gn_stats(const float* __restrict__ x,
                                                float* __restrict__ stats) {
    int b = blockIdx.x >> 3, g = blockIdx.x & 7;
    const float4* p = (const float4*)(x + ((size_t)b * CCH + (size_t)g * CPG) * NPIX);
    const int n4 = CPG * NPIX / 4;  // 65536
    float s = 0.f, ss = 0.f;
    for (int i = threadIdx.x; i < n4; i += 256) {
        float4 v = p[i];
        s  += v.x + v.y + v.z + v.w;
        ss += v.x*v.x + v.y*v.y + v.z*v.z + v.w*v.w;
    }
    __shared__ float rs[256], rss[256];
    rs[threadIdx.x] = s; rss[threadIdx.x] = ss;
    __syncthreads();
    for (int o = 128; o > 0; o >>= 1) {
        if (threadIdx.x < o) { rs[threadIdx.x] += rs[threadIdx.x+o]; rss[threadIdx.x] += rss[threadIdx.x+o]; }
        __syncthreads();
    }
    if (threadIdx.x == 0) {
        float inv = 1.0f / (float)(CPG * NPIX);
        float mu  = rs[0] * inv;
        float var = rss[0] * inv - mu * mu;
        stats[blockIdx.x * 2 + 0] = mu;
        stats[blockIdx.x * 2 + 1] = rsqrtf(var + EPSV);
    }
}

__global__ __launch_bounds__(256) void gn_apply(const float* __restrict__ x,
                                                const float* __restrict__ stats,
                                                const float* __restrict__ gw,
                                                const float* __restrict__ gb,
                                                float* __restrict__ h) {
    const size_t total4 = (size_t)BSZ * CCH * NPIX / 4;
    for (size_t i = (size_t)blockIdx.x * 256 + threadIdx.x; i < total4; i += (size_t)gridDim.x * 256) {
        size_t idx = i * 4;
        int c = (int)((idx >> 12) & (CCH - 1));
        int b = (int)(idx >> 21);
        int gi = b * NGRP + (c >> 6);
        float mu = stats[gi*2], rsg = stats[gi*2+1];
        float a = rsg * gw[c];
        float d = gb[c] - mu * a;
        float4 v = ((const float4*)x)[i];
        float4 o;
        o.x = v.x*a + d; o.y = v.y*a + d; o.z = v.z*a + d; o.w = v.w*a + d;
        ((float4*)h)[i] = o;
    }
}

// ------------------------------------------------- generic W[M,512] @ Bm GEMM
// out[b,m,n] = sum_k W[m,k]*Bm[b,k,n] + bias[m] (+ res[b,m,n])
__global__ __launch_bounds__(256) void gemm_wn(const float* __restrict__ W,
                                               const float* __restrict__ bias,
                                               const float* __restrict__ Bm,
                                               const float* __restrict__ res,
                                               float* __restrict__ out, int M) {
    const int K = 512, NN = NPIX;
    int b  = blockIdx.z;
    int m0 = blockIdx.y * 64;
    int n0 = blockIdx.x * 64;
    const float* Bb = Bm + (size_t)b * K * NN;

    __shared__ float As[16][68];
    __shared__ float Bs[16][68];

    int t = threadIdx.x;
    int ty = t >> 4, tx = t & 15;

    float acc[4][4];
    #pragma unroll
    for (int r = 0; r < 4; ++r)
        #pragma unroll
        for (int j = 0; j < 4; ++j) acc[r][j] = 0.f;

    for (int kc = 0; kc < K; kc += 16) {
        {   // A chunk: 64 m x 16 k
            int mm = t >> 2;
            int kk = (t & 3) * 4;
            float4 a = *(const float4*)&W[(size_t)(m0 + mm) * K + kc + kk];
            As[kk+0][mm] = a.x; As[kk+1][mm] = a.y; As[kk+2][mm] = a.z; As[kk+3][mm] = a.w;
        }
        {   // B chunk: 16 k x 64 n
            int kk = t >> 4;
            int nn = (t & 15) * 4;
            *(float4*)&Bs[kk][nn] = *(const float4*)&Bb[(size_t)(kc + kk) * NN + n0 + nn];
        }
        __syncthreads();
        #pragma unroll
        for (int kk = 0; kk < 16; ++kk) {
            float4 av = *(const float4*)&As[kk][ty*4];
            float4 bv = *(const float4*)&Bs[kk][tx*4];
            float ar[4] = {av.x, av.y, av.z, av.w};
            float br[4] = {bv.x, bv.y, bv.z, bv.w};
            #pragma unroll
            for (int r = 0; r < 4; ++r)
                #pragma unroll
                for (int j = 0; j < 4; ++j) acc[r][j] += ar[r] * br[j];
        }
        __syncthreads();
    }
    #pragma unroll
    for (int r = 0; r < 4; ++r) {
        int m = m0 + ty*4 + r;
        float bb = bias[m];
        size_t off = (size_t)b * M * NN + (size_t)m * NN + n0 + tx*4;
        float4 o;
        o.x = acc[r][0] + bb; o.y = acc[r][1] + bb; o.z = acc[r][2] + bb; o.w = acc[r][3] + bb;
        if (res) {
            float4 rv = *(const float4*)&res[off];
            o.x += rv.x; o.y += rv.y; o.z += rv.z; o.w += rv.w;
        }
        *(float4*)&out[off] = o;
    }
}

// --------------------------------------------- pass 1: softmax row stats
__global__ __launch_bounds__(256) void attn_stats(const float* __restrict__ qkv,
                                                  float* __restrict__ rowmax,
                                                  float* __restrict__ rowsum) {
    const int K = 512, NN = NPIX;
    int b  = blockIdx.y;
    int n0 = blockIdx.x * 64;
    const float* Qb = qkv + (size_t)b * 3 * K * NN;
    const float* Kb = Qb + (size_t)K * NN;

    __shared__ float qs[16][68];
    __shared__ float ks[16][68];
    __shared__ float red[64][17];
    __shared__ float rmax_s[64], rsum_s[64], nmax_s[64];

    int t = threadIdx.x;
    int ty = t >> 4, tx = t & 15;
    if (t < 64) { rmax_s[t] = -1e30f; rsum_s[t] = 0.f; }
    __syncthreads();

    for (int m0 = 0; m0 < NN; m0 += 64) {
        float s[4][4];
        #pragma unroll
        for (int r = 0; r < 4; ++r)
            #pragma unroll
            for (int j = 0; j < 4; ++j) s[r][j] = 0.f;

        for (int kc = 0; kc < K; kc += 16) {
            int kk = t >> 4;
            int xx = (t & 15) * 4;
            *(float4*)&qs[kk][xx] = *(const float4*)&Qb[(size_t)(kc+kk)*NN + n0 + xx];
            *(float4*)&ks[kk][xx] = *(const float4*)&Kb[(size_t)(kc+kk)*NN + m0 + xx];
            __syncthreads();
            #pragma unroll
            for (int k2 = 0; k2 < 16; ++k2) {
                float4 av = *(const float4*)&qs[k2][ty*4];
                float4 bv = *(const float4*)&ks[k2][tx*4];
                float ar[4] = {av.x, av.y, av.z, av.w};
                float br[4] = {bv.x, bv.y, bv.z, bv.w};
                #pragma unroll
                for (int r = 0; r < 4; ++r)
                    #pragma unroll
                    for (int j = 0; j < 4; ++j) s[r][j] += ar[r] * br[j];
            }
            __syncthreads();
        }
        // scale + local row max
        #pragma unroll
        for (int r = 0; r < 4; ++r) {
            float lm = -1e30f;
            #pragma unroll
            for (int j = 0; j < 4; ++j) { s[r][j] *= SCALE; lm = fmaxf(lm, s[r][j]); }
            red[ty*4 + r][tx] = lm;
        }
        __syncthreads();
        if (t < 64) {
            float m = red[t][0];
            #pragma unroll
            for (int i = 1; i < 16; ++i) m = fmaxf(m, red[t][i]);
            nmax_s[t] = fmaxf(rmax_s[t], m);
        }
        __syncthreads();
        #pragma unroll
        for (int r = 0; r < 4; ++r) {
            float nm = nmax_s[ty*4 + r];
            float ps = 0.f;
            #pragma unroll
            for (int j = 0; j < 4; ++j) ps += expf(s[r][j] - nm);
            red[ty*4 + r][tx] = ps;
        }
        __syncthreads();
        if (t < 64) {
            float pSum = 0.f;
            #pragma unroll
            for (int i = 0; i < 16; ++i) pSum += red[t][i];
            float nm = nmax_s[t];
            rsum_s[t] = rsum_s[t] * expf(rmax_s[t] - nm) + pSum;
            rmax_s[t] = nm;
        }
        __syncthreads();
    }
    if (t < 64) {
        rowmax[(size_t)b*NN + n0 + t] = rmax_s[t];
        rowsum[(size_t)b*NN + n0 + t] = rsum_s[t];
    }
}

// --------------------------------------------- pass 2: S recompute + PV
__global__ __launch_bounds__(256) void attn_pv(const float* __restrict__ qkv,
                                               const float* __restrict__ rowmax,
                                               const float* __restrict__ rowsum,
                                               float* __restrict__ hout) {
    const int K = 512, NN = NPIX;
    int b  = blockIdx.y;
    int n0 = blockIdx.x * 32;
    const float* Qb = qkv + (size_t)b * 3 * K * NN;
    const float* Kb = Qb + (size_t)K * NN;
    const float* Vb = Qb + (size_t)2 * K * NN;

    __shared__ float smem[13952];
    float* qs   = smem;          // [32][36]
    float* ks   = smem + 1152;   // [32][68]
    float* ps   = smem + 3328;   // [64][36]  ps[m][q]
    float* vs   = smem + 5632;   // [16][516]
    float* rm_s = smem + 13888;  // [32]
    float* ri_s = smem + 13920;  // [32]
    float* hs   = smem;          // epilogue alias [256][36]

    int t  = threadIdx.x;
    int ty = t >> 4, tx = t & 15;   // phase A: 32q x 64m, micro 2x4
    int tq = t >> 6, tc = t & 63;   // phase B: 512c x 32q, micro 8x8

    if (t < 32) {
        rm_s[t] = rowmax[(size_t)b*NN + n0 + t];
        ri_s[t] = 1.0f / rowsum[(size_t)b*NN + n0 + t];
    }

    float acc[8][8];
    #pragma unroll
    for (int i = 0; i < 8; ++i)
        #pragma unroll
        for (int j = 0; j < 8; ++j) acc[i][j] = 0.f;

    for (int m0 = 0; m0 < NN; m0 += 64) {
        // ---- phase A: S tile [32 q][64 m]
        float s[2][4] = {{0,0,0,0},{0,0,0,0}};
        for (int kc = 0; kc < K; kc += 32) {
            {
                int kk = t >> 3;
                int qq = (t & 7) * 4;
                *(float4*)&qs[kk*36 + qq] = *(const float4*)&Qb[(size_t)(kc+kk)*NN + n0 + qq];
            }
            #pragma unroll
            for (int l = 0; l < 2; ++l) {
                int e  = t*4 + l*1024;
                int kk = e >> 6, mm = e & 63;
                *(float4*)&ks[kk*68 + mm] = *(const float4*)&Kb[(size_t)(kc+kk)*NN + m0 + mm];
            }
            __syncthreads();
            #pragma unroll
            for (int kk = 0; kk < 32; ++kk) {
                float a0 = qs[kk*36 + 2*ty];
                float a1 = qs[kk*36 + 2*ty + 1];
                float4 bv = *(const float4*)&ks[kk*68 + 4*tx];
                s[0][0] += a0*bv.x; s[0][1] += a0*bv.y; s[0][2] += a0*bv.z; s[0][3] += a0*bv.w;
                s[1][0] += a1*bv.x; s[1][1] += a1*bv.y; s[1][2] += a1*bv.z; s[1][3] += a1*bv.w;
            }
            __syncthreads();
        }
        // ---- softmax into ps[m][q]
        #pragma unroll
        for (int r = 0; r < 2; ++r) {
            int q = 2*ty + r;
            float nm = rm_s[q], riv = ri_s[q];
            #pragma unroll
            for (int j = 0; j < 4; ++j)
                ps[(4*tx + j)*36 + q] = expf(s[r][j]*SCALE - nm) * riv;
        }
        __syncthreads();
        // ---- phase B: acc[c][q] += V[c, mtile] * P^T
        for (int mc = 0; mc < 64; mc += 16) {
            #pragma unroll
            for (int l = 0; l < 8; ++l) {
                int e = t + l*256;
                int c = e >> 2;
                int mj4 = (e & 3) * 4;
                float4 vv = *(const float4*)&Vb[(size_t)c*NN + m0 + mc + mj4];
                vs[(mj4+0)*516 + c] = vv.x;
                vs[(mj4+1)*516 + c] = vv.y;
                vs[(mj4+2)*516 + c] = vv.z;
                vs[(mj4+3)*516 + c] = vv.w;
            }
            __syncthreads();
            #pragma unroll
            for (int mj = 0; mj < 16; ++mj) {
                float4 p0 = *(const float4*)&ps[(mc+mj)*36 + tq*8];
                float4 p1 = *(const float4*)&ps[(mc+mj)*36 + tq*8 + 4];
                float pv[8] = {p0.x,p0.y,p0.z,p0.w,p1.x,p1.y,p1.z,p1.w};
                float vr[8];
                #pragma unroll
                for (int i = 0; i < 8; ++i) vr[i] = vs[mj*516 + tc + 64*i];
                #pragma unroll
                for (int i = 0; i < 8; ++i)
                    #pragma unroll
                    for (int j = 0; j < 8; ++j) acc[i][j] += vr[i]*pv[j];
            }
            __syncthreads();
        }
    }
    // ---- epilogue: LDS transpose, coalesced store (two c-halves)
    for (int hf = 0; hf < 2; ++hf) {
        __syncthreads();
        #pragma unroll
        for (int i = 0; i < 4; ++i)
            #pragma unroll
            for (int j = 0; j < 8; ++j)
                hs[(tc + 64*i)*36 + tq*8 + j] = acc[4*hf + i][j];
        __syncthreads();
        #pragma unroll
        for (int l = 0; l < 8; ++l) {
            int e  = t + l*256;
            int cl = e >> 3;
            int qq = (e & 7) * 4;
            float4 o;
            o.x = hs[cl*36 + qq + 0];
            o.y = hs[cl*36 + qq + 1];
            o.z = hs[cl*36 + qq + 2];
            o.w = hs[cl*36 + qq + 3];
            *(float4*)&hout[(size_t)b*K*NN + (size_t)(hf*256 + cl)*NN + n0 + qq] = o;
        }
    }
}

extern "C" void kernel_launch(void* const* d_in, const int* in_sizes, int n_in,
                              void* d_out, int out_size, void* d_ws, size_t ws_size,
                              hipStream_t stream) {
    const float* x      = (const float*)d_in[0];
    const float* gn_w   = (const float*)d_in[1];
    const float* gn_b   = (const float*)d_in[2];
    const float* qkv_w  = (const float*)d_in[3];
    const float* qkv_b  = (const float*)d_in[4];
    const float* proj_w = (const float*)d_in[5];
    const float* proj_b = (const float*)d_in[6];
    float* out = (float*)d_out;
    float* ws  = (float*)d_ws;

    // ws layout (floats): stats@0, rowmax@1024, rowsum@17408,
    // h/hout@33792 (8388608), qkv@8422400 (25165824)  -> ~134.4 MB total
    float* stats  = ws;
    float* rowmax = ws + 1024;
    float* rowsum = ws + 17408;
    float* h      = ws + 33792;           // reused as hout after QKV gemm
    float* qkvb   = ws + 33792 + 8388608;

    gn_stats<<<32, 256, 0, stream>>>(x, stats);
    gn_apply<<<2048, 256, 0, stream>>>(x, stats, gn_w, gn_b, h);
    gemm_wn<<<dim3(64, 24, 4), 256, 0, stream>>>(qkv_w, qkv_b, h, nullptr, qkvb, 1536);
    attn_stats<<<dim3(64, 4), 256, 0, stream>>>(qkvb, rowmax, rowsum);
    attn_pv<<<dim3(128, 4), 256, 0, stream>>>(qkvb, rowmax, rowsum, h);
    gemm_wn<<<dim3(64, 8, 4), 256, 0, stream>>>(proj_w, proj_b, h, x, out, 512);
}

// Round 3
// 798.596 us; speedup vs baseline: 8.1527x; 8.1527x over previous
//
#include <hip/hip_runtime.h>
#include <math.h>

#define SCALE 0.044194173824159216f  // 512^-0.5

typedef __bf16 bf16x8 __attribute__((ext_vector_type(8)));
typedef __bf16 bf16x4 __attribute__((ext_vector_type(4)));
typedef float  f32x16 __attribute__((ext_vector_type(16)));

// ---------------------------------------------------------------- GroupNorm stats
__global__ __launch_bounds__(256) void gn_stats(const float* __restrict__ x,
                                                float* __restrict__ stats) {
    int b = blockIdx.x >> 3, g = blockIdx.x & 7;
    const float4* p = (const float4*)(x + ((size_t)b * 512 + (size_t)g * 64) * 4096);
    const int n4 = 64 * 4096 / 4;
    float s = 0.f, ss = 0.f;
    for (int i = threadIdx.x; i < n4; i += 256) {
        float4 v = p[i];
        s  += v.x + v.y + v.z + v.w;
        ss += v.x*v.x + v.y*v.y + v.z*v.z + v.w*v.w;
    }
    __shared__ float rs[256], rss[256];
    rs[threadIdx.x] = s; rss[threadIdx.x] = ss;
    __syncthreads();
    for (int o = 128; o > 0; o >>= 1) {
        if (threadIdx.x < o) { rs[threadIdx.x] += rs[threadIdx.x+o]; rss[threadIdx.x] += rss[threadIdx.x+o]; }
        __syncthreads();
    }
    if (threadIdx.x == 0) {
        float inv = 1.0f / (float)(64 * 4096);
        float mu  = rs[0] * inv;
        float var = rss[0] * inv - mu * mu;
        stats[blockIdx.x * 2 + 0] = mu;
        stats[blockIdx.x * 2 + 1] = rsqrtf(var + 1e-5f);
    }
}

// --------------------------------------- GN apply + transpose -> hT [B][4096][512] bf16
__global__ __launch_bounds__(256) void gn_apply_t(const float* __restrict__ x,
                                                  const float* __restrict__ stats,
                                                  const float* __restrict__ gw,
                                                  const float* __restrict__ gb,
                                                  __bf16* __restrict__ hT) {
    __shared__ __bf16 tile[64][88];   // 176B pitch: 16B-aligned rows, spread banks
    int b = blockIdx.z, c0 = blockIdx.y * 64, n0 = blockIdx.x * 64;
    int t = threadIdx.x;
    float mu  = stats[(b*8 + blockIdx.y)*2];
    float rsg = stats[(b*8 + blockIdx.y)*2 + 1];
    int c = t >> 2, ns = t & 3;
    float a = gw[c0+c] * rsg;
    float d = gb[c0+c] - mu * a;
    const float* xr = x + ((size_t)b*512 + c0 + c)*4096 + n0 + ns*16;
    #pragma unroll
    for (int e4 = 0; e4 < 4; ++e4) {
        float4 v = *(const float4*)(xr + e4*4);
        tile[ns*16 + e4*4 + 0][c] = (__bf16)(v.x*a + d);
        tile[ns*16 + e4*4 + 1][c] = (__bf16)(v.y*a + d);
        tile[ns*16 + e4*4 + 2][c] = (__bf16)(v.z*a + d);
        tile[ns*16 + e4*4 + 3][c] = (__bf16)(v.w*a + d);
    }
    __syncthreads();
    int n = t >> 2, cs = t & 3;
    __bf16* dst = hT + ((size_t)b*4096 + n0 + n)*512 + c0 + cs*16;
    *(uint4*)(dst)     = *(const uint4*)(&tile[n][cs*16]);
    *(uint4*)(dst + 8) = *(const uint4*)(&tile[n][cs*16 + 8]);
}

// ---------------------------------------------------------------- weight f32->bf16
__global__ __launch_bounds__(256) void wconv(const float* __restrict__ src,
                                             __bf16* __restrict__ dst, int n) {
    int i = (blockIdx.x*256 + threadIdx.x) * 4;
    if (i < n) {
        float4 v = *(const float4*)(src + i);
        dst[i+0] = (__bf16)v.x; dst[i+1] = (__bf16)v.y;
        dst[i+2] = (__bf16)v.z; dst[i+3] = (__bf16)v.w;
    }
}

// ---------------------------------------------------------------- 128x128 MFMA GEMM
// D[i][j] = sum_k A[i][k]*B[j][k] ; A,B bf16 row-major lda=ldb=512 (k contiguous).
template<int MODE>
__global__ __launch_bounds__(512) void mm128(const __bf16* __restrict__ A, size_t sA,
                                             const __bf16* __restrict__ B, size_t sB,
                                             const float* __restrict__ bias,
                                             const float* __restrict__ res, size_t sR,
                                             void* __restrict__ out, size_t sO, int ldo) {
    __shared__ __bf16 As[2][128][64];
    __shared__ __bf16 Bs[2][128][64];
    const int t = threadIdx.x, w = t >> 6, l = t & 63;
    const int l31 = l & 31, lh = l >> 5;
    const int j0 = blockIdx.x*128, i0 = blockIdx.y*128, bz = blockIdx.z;
    const __bf16* Ab = A + sA * bz;
    const __bf16* Bb = B + sB * bz;
    const int iw = w & 1, jw = w >> 1;

    const int srow = t >> 3, sslot = t & 7;
    const int sswz = sslot ^ (srow & 7);
    const int srow2 = (t + 512) >> 3, sslot2 = (t + 512) & 7;
    const int sswz2 = sslot2 ^ (srow2 & 7);

    f32x16 acc[2];
    #pragma unroll
    for (int i = 0; i < 2; ++i)
        #pragma unroll
        for (int r = 0; r < 16; ++r) acc[i][r] = 0.f;

    {
        uint4 a0 = *(const uint4*)(Ab + (size_t)(i0 + srow)*512 + sslot*8);
        uint4 a1 = *(const uint4*)(Ab + (size_t)(i0 + srow2)*512 + sslot2*8);
        uint4 b0 = *(const uint4*)(Bb + (size_t)(j0 + srow)*512 + sslot*8);
        uint4 b1 = *(const uint4*)(Bb + (size_t)(j0 + srow2)*512 + sslot2*8);
        *(uint4*)((char*)&As[0][0][0] + srow*128  + sswz*16)  = a0;
        *(uint4*)((char*)&As[0][0][0] + srow2*128 + sswz2*16) = a1;
        *(uint4*)((char*)&Bs[0][0][0] + srow*128  + sswz*16)  = b0;
        *(uint4*)((char*)&Bs[0][0][0] + srow2*128 + sswz2*16) = b1;
    }
    __syncthreads();

    #pragma unroll
    for (int cc = 0; cc < 8; ++cc) {
        uint4 na0, na1, nb0, nb1;
        if (cc < 7) {
            int c0 = (cc + 1) * 64;
            na0 = *(const uint4*)(Ab + (size_t)(i0 + srow)*512  + c0 + sslot*8);
            na1 = *(const uint4*)(Ab + (size_t)(i0 + srow2)*512 + c0 + sslot2*8);
            nb0 = *(const uint4*)(Bb + (size_t)(j0 + srow)*512  + c0 + sslot*8);
            nb1 = *(const uint4*)(Bb + (size_t)(j0 + srow2)*512 + c0 + sslot2*8);
        }
        const char* Ac = (const char*)&As[cc & 1][0][0];
        const char* Bc = (const char*)&Bs[cc & 1][0][0];
        #pragma unroll
        for (int ks = 0; ks < 4; ++ks) {
            int brow = jw*32 + l31;
            int bs = (2*ks + lh) ^ (brow & 7);
            bf16x8 bf = *(const bf16x8*)(Bc + brow*128 + bs*16);
            #pragma unroll
            for (int tt = 0; tt < 2; ++tt) {
                int arow = iw*64 + tt*32 + l31;
                int as = (2*ks + lh) ^ (arow & 7);
                bf16x8 af = *(const bf16x8*)(Ac + arow*128 + as*16);
                acc[tt] = __builtin_amdgcn_mfma_f32_32x32x16_bf16(af, bf, acc[tt], 0, 0, 0);
            }
        }
        __syncthreads();   // safety: all reads of buf cc&1 complete before any next-buf write
        if (cc < 7) {
            char* An = (char*)&As[(cc + 1) & 1][0][0];
            char* Bn = (char*)&Bs[(cc + 1) & 1][0][0];
            *(uint4*)(An + srow*128  + sswz*16)  = na0;
            *(uint4*)(An + srow2*128 + sswz2*16) = na1;
            *(uint4*)(Bn + srow*128  + sswz*16)  = nb0;
            *(uint4*)(Bn + srow2*128 + sswz2*16) = nb1;
        }
        __syncthreads();
    }

    const int gj = j0 + jw*32 + l31;
    float bcol = (MODE == 0) ? bias[gj] : 0.f;
    #pragma unroll
    for (int tt = 0; tt < 2; ++tt) {
        #pragma unroll
        for (int r = 0; r < 16; ++r) {
            int row = iw*64 + tt*32 + (r & 3) + 8*(r >> 2) + 4*lh;
            int gi = i0 + row;
            float v = acc[tt][r];
            if constexpr (MODE == 0) {
                v += bcol;
                ((__bf16*)out)[sO*bz + (size_t)gi*ldo + gj] = (__bf16)v;
            } else if constexpr (MODE == 1) {
                v += bias[gi];
                ((__bf16*)out)[sO*bz + (size_t)gi*ldo + gj] = (__bf16)v;
            } else {
                v += bias[gi] + res[sR*bz + (size_t)gi*ldo + gj];
                ((float*)out)[sO*bz + (size_t)gi*ldo + gj] = v;
            }
        }
    }
}

// ---------------------------------------------------------------- fused attention
// qkT [B][4096][1024] (q cols 0..511, k cols 512..1023), V [B][512][4096], OT [B][4096][512]
// Dynamic LDS, NO aliasing:
//   Ks   @0      : [32 keys][512c] bf16, 64 slots/row of 16B, slot ^= (key&7)   (32768 B)
//   vb   @32768  : [512 c][80B] keys at bytes 0..63                              (40960 B)
//   sred @73728  : [4][64][36] f32 partial S                                     (36864 B)
//   plds @110592 : [64 q][80B] P bf16, keys at bytes 0..63                       (5120 B)
//   lac  @115712 : [512] f32 exp-sum partials                                    (2048 B)
//   linv @117760 : [64] f32                                                      (256 B)
#define ATTN_LDS 118016
__global__ __launch_bounds__(512) void attn_fused(const __bf16* __restrict__ qkT,
                                                  const __bf16* __restrict__ V,
                                                  __bf16* __restrict__ OT) {
    extern __shared__ char smem[];
    char*  KsB  = smem;
    char*  vb   = smem + 32768;
    float* sred = (float*)(smem + 73728);
    char*  plds = smem + 110592;
    float* lac  = (float*)(smem + 115712);
    float* linv = (float*)(smem + 117760);

    const int t = threadIdx.x, w = t >> 6, l = t & 63;
    const int l31 = l & 31, lh = l >> 5;
    const int b = blockIdx.y;
    const int n0 = blockIdx.x * 64;
    const __bf16* qkTb = qkT + (size_t)b * 4096 * 1024;
    const __bf16* Vb   = V   + (size_t)b * 512 * 4096;

    const int na = w & 1, ka = w >> 1;   // S roles: q-half, c-quarter
    const int cu = w >> 1;               // PV role: c-quarter

    lac[t] = 0.f;

    // Q fragments: rows n0+na*32+l31, c-quarter ka (8 k-steps of 16)
    bf16x8 q[8];
    {
        const __bf16* qrow = qkTb + (size_t)(n0 + na*32 + l31)*1024 + ka*128 + lh*8;
        #pragma unroll
        for (int ck = 0; ck < 8; ++ck) q[ck] = *(const bf16x8*)(qrow + ck*16);
    }

    f32x16 acc[4];
    #pragma unroll
    for (int i = 0; i < 4; ++i)
        #pragma unroll
        for (int r = 0; r < 16; ++r) acc[i][r] = 0.f;

    const int key_s = t >> 4, slot_s = t & 15;   // K staging: 32 rows x 4 slots each
    const int vrow0 = t >> 2, vslot = t & 3;     // V staging: 4 rows x 1 slot each

    // prologue: load tile 0 into regs
    uint4 Kreg[4], Vreg[4];
    #pragma unroll
    for (int j = 0; j < 4; ++j)
        Kreg[j] = *(const uint4*)(qkTb + (size_t)key_s*1024 + 512 + (slot_s + j*16)*8);
    #pragma unroll
    for (int k2 = 0; k2 < 4; ++k2)
        Vreg[k2] = *(const uint4*)(Vb + (size_t)(vrow0 + k2*128)*4096 + vslot*8);

    for (int m0 = 0; m0 < 4096; m0 += 32) {
        // ---- stage current tile (regs -> LDS)
        #pragma unroll
        for (int j = 0; j < 4; ++j) {
            int s = slot_s + j*16;
            *(uint4*)(KsB + key_s*1024 + (s ^ (key_s & 7))*16) = Kreg[j];
        }
        #pragma unroll
        for (int k2 = 0; k2 < 4; ++k2)
            *(uint4*)(vb + (vrow0 + k2*128)*80 + vslot*16) = Vreg[k2];
        __syncthreads();                                   // B1: tile staged

        // ---- prefetch next tile to regs (latency hidden under S-MFMA)
        if (m0 < 4064) {
            #pragma unroll
            for (int j = 0; j < 4; ++j)
                Kreg[j] = *(const uint4*)(qkTb + (size_t)(m0 + 32 + key_s)*1024 + 512 + (slot_s + j*16)*8);
            #pragma unroll
            for (int k2 = 0; k2 < 4; ++k2)
                Vreg[k2] = *(const uint4*)(Vb + (size_t)(vrow0 + k2*128)*4096 + m0 + 32 + vslot*8);
        }

        // ---- S-MFMA: all 8 waves, partial over c-quarter ka
        f32x16 sv;
        #pragma unroll
        for (int r = 0; r < 16; ++r) sv[r] = 0.f;
        #pragma unroll
        for (int ck = 0; ck < 8; ++ck) {
            int sl = (ka*16 + ck*2 + lh) ^ (l31 & 7);
            bf16x8 kf = *(const bf16x8*)(KsB + l31*1024 + sl*16);
            sv = __builtin_amdgcn_mfma_f32_32x32x16_bf16(q[ck], kf, sv, 0, 0, 0);
        }
        {
            float* sr = sred + ka*2304;
            #pragma unroll
            for (int r = 0; r < 16; ++r) {
                int row = na*32 + (r & 3) + 8*(r >> 2) + 4*lh;
                sr[row*36 + l31] = sv[r];
            }
        }
        __syncthreads();                                   // B2: sred complete

        // ---- softmax (no max subtraction; scores small)
        {
            int row = t >> 3, c0 = (t & 7)*4;
            float4 s0 = *(const float4*)(sred + 0*2304 + row*36 + c0);
            float4 s1 = *(const float4*)(sred + 1*2304 + row*36 + c0);
            float4 s2 = *(const float4*)(sred + 2*2304 + row*36 + c0);
            float4 s3 = *(const float4*)(sred + 3*2304 + row*36 + c0);
            float e0 = __expf((s0.x + s1.x + s2.x + s3.x) * SCALE);
            float e1 = __expf((s0.y + s1.y + s2.y + s3.y) * SCALE);
            float e2 = __expf((s0.z + s1.z + s2.z + s3.z) * SCALE);
            float e3 = __expf((s0.w + s1.w + s2.w + s3.w) * SCALE);
            lac[t] += e0 + e1 + e2 + e3;
            bf16x4 pb; pb[0] = (__bf16)e0; pb[1] = (__bf16)e1; pb[2] = (__bf16)e2; pb[3] = (__bf16)e3;
            *(bf16x4*)(plds + row*80 + c0*2) = pb;
        }
        __syncthreads();                                   // B3: P ready

        // ---- PV: acc[q][c] += P[q][key] * V[c][key]
        #pragma unroll
        for (int kk = 0; kk < 2; ++kk) {
            bf16x8 pa = *(const bf16x8*)(plds + (na*32 + l31)*80 + kk*32 + lh*16);
            #pragma unroll
            for (int ct = 0; ct < 4; ++ct) {
                int vr = cu*128 + ct*32 + l31;
                bf16x8 vf = *(const bf16x8*)(vb + vr*80 + kk*32 + lh*16);
                acc[ct] = __builtin_amdgcn_mfma_f32_32x32x16_bf16(pa, vf, acc[ct], 0, 0, 0);
            }
        }
        __syncthreads();                                   // B4: PV reads done
    }

    if (t < 64) {
        float s = 0.f;
        #pragma unroll
        for (int j = 0; j < 8; ++j) s += lac[t*8 + j];
        linv[t] = 1.f / s;
    }
    __syncthreads();

    #pragma unroll
    for (int ct = 0; ct < 4; ++ct) {
        #pragma unroll
        for (int r = 0; r < 16; ++r) {
            int row = na*32 + (r & 3) + 8*(r >> 2) + 4*lh;
            int col = cu*128 + ct*32 + l31;
            float v = acc[ct][r] * linv[row];
            OT[(size_t)b*4096*512 + (size_t)(n0 + row)*512 + col] = (__bf16)v;
        }
    }
}

extern "C" void kernel_launch(void* const* d_in, const int* in_sizes, int n_in,
                              void* d_out, int out_size, void* d_ws, size_t ws_size,
                              hipStream_t stream) {
    const float* x      = (const float*)d_in[0];
    const float* gn_w   = (const float*)d_in[1];
    const float* gn_b   = (const float*)d_in[2];
    const float* qkv_w  = (const float*)d_in[3];
    const float* qkv_b  = (const float*)d_in[4];
    const float* proj_w = (const float*)d_in[5];
    const float* proj_b = (const float*)d_in[6];

    char* w8 = (char*)d_ws;
    __bf16* hT   = (__bf16*)(w8);                 // 16 MB  [B][4096][512]
    __bf16* qkT  = (__bf16*)(w8 + 16777216);      // 32 MB  [B][4096][1024]
    __bf16* Vbuf = (__bf16*)(w8 + 50331648);      // 16 MB  [B][512][4096]
    __bf16* OT   = (__bf16*)(w8 + 67108864);      // 16 MB  [B][4096][512]
    __bf16* wq   = (__bf16*)(w8 + 83886080);      // 1.5 MB [1536][512]
    __bf16* pw   = (__bf16*)(w8 + 85458944);      // 0.5 MB [512][512]
    float*  st   = (float*)(w8 + 85983232);       // stats

    hipFuncSetAttribute((const void*)attn_fused,
                        hipFuncAttributeMaxDynamicSharedMemorySize, ATTN_LDS);

    wconv<<<768, 256, 0, stream>>>(qkv_w, wq, 1536*512);
    wconv<<<256, 256, 0, stream>>>(proj_w, pw, 512*512);
    gn_stats<<<32, 256, 0, stream>>>(x, st);
    gn_apply_t<<<dim3(64, 8, 4), 256, 0, stream>>>(x, st, gn_w, gn_b, hT);
    mm128<0><<<dim3(8, 32, 4), 512, 0, stream>>>(hT, (size_t)4096*512, wq, 0,
                                                 qkv_b, nullptr, 0, qkT, (size_t)4096*1024, 1024);
    mm128<1><<<dim3(32, 4, 4), 512, 0, stream>>>(wq + (size_t)1024*512, 0, hT, (size_t)4096*512,
                                                 qkv_b + 1024, nullptr, 0, Vbuf, (size_t)512*4096, 4096);
    attn_fused<<<dim3(64, 4), 512, ATTN_LDS, stream>>>(qkT, Vbuf, OT);
    mm128<2><<<dim3(32, 4, 4), 512, 0, stream>>>(pw, 0, OT, (size_t)4096*512,
                                                 proj_b, x, (size_t)512*4096, (float*)d_out, (size_t)512*4096, 4096);
}

// Round 4
// 401.252 us; speedup vs baseline: 16.2260x; 1.9903x over previous
//
#include <hip/hip_runtime.h>
#include <math.h>

#define SCALE 0.044194173824159216f  // 512^-0.5

typedef __bf16 bf16x8 __attribute__((ext_vector_type(8)));
typedef float  f32x16 __attribute__((ext_vector_type(16)));

// ---------------------------------------------------------------- GroupNorm stats
__global__ __launch_bounds__(256) void gn_stats(const float* __restrict__ x,
                                                float* __restrict__ stats) {
    int b = blockIdx.x >> 3, g = blockIdx.x & 7;
    const float4* p = (const float4*)(x + ((size_t)b * 512 + (size_t)g * 64) * 4096);
    const int n4 = 64 * 4096 / 4;
    float s = 0.f, ss = 0.f;
    for (int i = threadIdx.x; i < n4; i += 256) {
        float4 v = p[i];
        s  += v.x + v.y + v.z + v.w;
        ss += v.x*v.x + v.y*v.y + v.z*v.z + v.w*v.w;
    }
    __shared__ float rs[256], rss[256];
    rs[threadIdx.x] = s; rss[threadIdx.x] = ss;
    __syncthreads();
    for (int o = 128; o > 0; o >>= 1) {
        if (threadIdx.x < o) { rs[threadIdx.x] += rs[threadIdx.x+o]; rss[threadIdx.x] += rss[threadIdx.x+o]; }
        __syncthreads();
    }
    if (threadIdx.x == 0) {
        float inv = 1.0f / (float)(64 * 4096);
        float mu  = rs[0] * inv;
        float var = rss[0] * inv - mu * mu;
        stats[blockIdx.x * 2 + 0] = mu;
        stats[blockIdx.x * 2 + 1] = rsqrtf(var + 1e-5f);
    }
}

// --------------------------------------- GN apply + transpose -> hT [B][4096][512] bf16
__global__ __launch_bounds__(256) void gn_apply_t(const float* __restrict__ x,
                                                  const float* __restrict__ stats,
                                                  const float* __restrict__ gw,
                                                  const float* __restrict__ gb,
                                                  __bf16* __restrict__ hT) {
    __shared__ __bf16 tile[64][88];   // 176B pitch: 16B-aligned rows
    int b = blockIdx.z, c0 = blockIdx.y * 64, n0 = blockIdx.x * 64;
    int t = threadIdx.x;
    float mu  = stats[(b*8 + blockIdx.y)*2];
    float rsg = stats[(b*8 + blockIdx.y)*2 + 1];
    int c = t >> 2, ns = t & 3;
    float a = gw[c0+c] * rsg;
    float d = gb[c0+c] - mu * a;
    const float* xr = x + ((size_t)b*512 + c0 + c)*4096 + n0 + ns*16;
    #pragma unroll
    for (int e4 = 0; e4 < 4; ++e4) {
        float4 v = *(const float4*)(xr + e4*4);
        tile[ns*16 + e4*4 + 0][c] = (__bf16)(v.x*a + d);
        tile[ns*16 + e4*4 + 1][c] = (__bf16)(v.y*a + d);
        tile[ns*16 + e4*4 + 2][c] = (__bf16)(v.z*a + d);
        tile[ns*16 + e4*4 + 3][c] = (__bf16)(v.w*a + d);
    }
    __syncthreads();
    int n = t >> 2, cs = t & 3;
    __bf16* dst = hT + ((size_t)b*4096 + n0 + n)*512 + c0 + cs*16;
    *(uint4*)(dst)     = *(const uint4*)(&tile[n][cs*16]);
    *(uint4*)(dst + 8) = *(const uint4*)(&tile[n][cs*16 + 8]);
}

// ---------------------------------------------------------------- weight f32->bf16
__global__ __launch_bounds__(256) void wconv(const float* __restrict__ src,
                                             __bf16* __restrict__ dst, int n) {
    int i = (blockIdx.x*256 + threadIdx.x) * 4;
    if (i < n) {
        float4 v = *(const float4*)(src + i);
        dst[i+0] = (__bf16)v.x; dst[i+1] = (__bf16)v.y;
        dst[i+2] = (__bf16)v.z; dst[i+3] = (__bf16)v.w;
    }
}

// ---------------------------------------------------------------- 128x128 MFMA GEMM
// D[i][j] = sum_k A[i][k]*B[j][k]; A,B bf16 row-major, k contiguous.
// MODE 0: +bias[j], bf16 out                   (QKV -> qkT)
// MODE 1: +bias[i], bf16 out                   (V)
// MODE 2: +bias[i]+res, f32 out                (proj + residual)
// MODE 3: exp(acc*SCALE) -> bf16 P + rowpart   (S-GEMM)
// MODE 4: acc * 1/rowsum -> bf16 out           (PV-GEMM)
template<int MODE>
__global__ __launch_bounds__(512, 4) void mm128(
        const __bf16* __restrict__ A, int lda, size_t sA,
        const __bf16* __restrict__ B, int ldb, size_t sB,
        int Kdim,
        const float* __restrict__ bias,
        const float* __restrict__ res, size_t sR,
        void* __restrict__ out, int ldo, size_t sO,
        float* __restrict__ rowpart) {
    __shared__ __bf16 As[2][128][64];
    __shared__ __bf16 Bs[2][128][64];
    __shared__ float  redp[128*4];    // MODE 3 cross-wave rowsum partials
    __shared__ float  rsum[128];      // MODE 4 1/rowsum

    const int t = threadIdx.x, w = t >> 6, l = t & 63;
    const int l31 = l & 31, lh = l >> 5;
    const int j0 = blockIdx.x*128, i0 = blockIdx.y*128, bz = blockIdx.z;
    const __bf16* Ab = A + sA * bz;
    const __bf16* Bb = B + sB * bz;
    const int iw = w & 1, jw = w >> 1;

    if constexpr (MODE == 4) {
        if (t < 128) {
            const float* rp = rowpart + (size_t)bz*131072 + i0 + t;
            float s = 0.f;
            #pragma unroll
            for (int jb = 0; jb < 32; ++jb) s += rp[jb*4096];
            rsum[t] = 1.0f / s;
        }
    }

    const int srow = t >> 3, sslot = t & 7;
    const int sswz = sslot ^ (srow & 7);
    const int srow2 = (t + 512) >> 3, sslot2 = (t + 512) & 7;
    const int sswz2 = sslot2 ^ (srow2 & 7);

    f32x16 acc[2];
    #pragma unroll
    for (int i = 0; i < 2; ++i)
        #pragma unroll
        for (int r = 0; r < 16; ++r) acc[i][r] = 0.f;

    {   // stage chunk 0
        uint4 a0 = *(const uint4*)(Ab + (size_t)(i0 + srow)*lda + sslot*8);
        uint4 a1 = *(const uint4*)(Ab + (size_t)(i0 + srow2)*lda + sslot2*8);
        uint4 b0 = *(const uint4*)(Bb + (size_t)(j0 + srow)*ldb + sslot*8);
        uint4 b1 = *(const uint4*)(Bb + (size_t)(j0 + srow2)*ldb + sslot2*8);
        *(uint4*)((char*)&As[0][0][0] + srow*128  + sswz*16)  = a0;
        *(uint4*)((char*)&As[0][0][0] + srow2*128 + sswz2*16) = a1;
        *(uint4*)((char*)&Bs[0][0][0] + srow*128  + sswz*16)  = b0;
        *(uint4*)((char*)&Bs[0][0][0] + srow2*128 + sswz2*16) = b1;
    }
    __syncthreads();

    const int nch = Kdim >> 6;
    for (int cc = 0; cc < nch; ++cc) {
        uint4 na0, na1, nb0, nb1;
        if (cc + 1 < nch) {
            int c0 = (cc + 1) * 64;
            na0 = *(const uint4*)(Ab + (size_t)(i0 + srow)*lda  + c0 + sslot*8);
            na1 = *(const uint4*)(Ab + (size_t)(i0 + srow2)*lda + c0 + sslot2*8);
            nb0 = *(const uint4*)(Bb + (size_t)(j0 + srow)*ldb  + c0 + sslot*8);
            nb1 = *(const uint4*)(Bb + (size_t)(j0 + srow2)*ldb + c0 + sslot2*8);
        }
        const char* Ac = (const char*)&As[cc & 1][0][0];
        const char* Bc = (const char*)&Bs[cc & 1][0][0];
        #pragma unroll
        for (int ks = 0; ks < 4; ++ks) {
            int brow = jw*32 + l31;
            int bs = (2*ks + lh) ^ (brow & 7);
            bf16x8 bf = *(const bf16x8*)(Bc + brow*128 + bs*16);
            #pragma unroll
            for (int tt = 0; tt < 2; ++tt) {
                int arow = iw*64 + tt*32 + l31;
                int as = (2*ks + lh) ^ (arow & 7);
                bf16x8 af = *(const bf16x8*)(Ac + arow*128 + as*16);
                acc[tt] = __builtin_amdgcn_mfma_f32_32x32x16_bf16(af, bf, acc[tt], 0, 0, 0);
            }
        }
        __syncthreads();   // all reads of buf cc&1 done before next-buf write
        if (cc + 1 < nch) {
            char* An = (char*)&As[(cc + 1) & 1][0][0];
            char* Bn = (char*)&Bs[(cc + 1) & 1][0][0];
            *(uint4*)(An + srow*128  + sswz*16)  = na0;
            *(uint4*)(An + srow2*128 + sswz2*16) = na1;
            *(uint4*)(Bn + srow*128  + sswz*16)  = nb0;
            *(uint4*)(Bn + srow2*128 + sswz2*16) = nb1;
        }
        __syncthreads();
    }

    const int gj = j0 + jw*32 + l31;

    if constexpr (MODE == 3) {
        // exp + store P + rowsum partials (no atomics)
        #pragma unroll
        for (int tt = 0; tt < 2; ++tt) {
            float es[16];
            #pragma unroll
            for (int r = 0; r < 16; ++r) {
                float e = __expf(acc[tt][r] * SCALE);
                es[r] = e;
                int row = iw*64 + tt*32 + (r & 3) + 8*(r >> 2) + 4*lh;
                ((__bf16*)out)[sO*bz + (size_t)(i0 + row)*ldo + gj] = (__bf16)e;
            }
            #pragma unroll
            for (int m = 1; m < 32; m <<= 1)
                #pragma unroll
                for (int r = 0; r < 16; ++r) es[r] += __shfl_xor(es[r], m);
            if (l31 == 0) {
                #pragma unroll
                for (int r = 0; r < 16; ++r) {
                    int row = iw*64 + tt*32 + (r & 3) + 8*(r >> 2) + 4*lh;
                    redp[row*4 + jw] = es[r];
                }
            }
        }
        __syncthreads();
        if (t < 128) {
            float s = redp[t*4+0] + redp[t*4+1] + redp[t*4+2] + redp[t*4+3];
            rowpart[(size_t)bz*131072 + (size_t)blockIdx.x*4096 + i0 + t] = s;
        }
        return;
    }

    float bcol = (MODE == 0) ? bias[gj] : 0.f;
    #pragma unroll
    for (int tt = 0; tt < 2; ++tt) {
        #pragma unroll
        for (int r = 0; r < 16; ++r) {
            int row = iw*64 + tt*32 + (r & 3) + 8*(r >> 2) + 4*lh;
            int gi = i0 + row;
            float v = acc[tt][r];
            if constexpr (MODE == 0) {
                v += bcol;
                ((__bf16*)out)[sO*bz + (size_t)gi*ldo + gj] = (__bf16)v;
            } else if constexpr (MODE == 1) {
                v += bias[gi];
                ((__bf16*)out)[sO*bz + (size_t)gi*ldo + gj] = (__bf16)v;
            } else if constexpr (MODE == 2) {
                v += bias[gi] + res[sR*bz + (size_t)gi*ldo + gj];
                ((float*)out)[sO*bz + (size_t)gi*ldo + gj] = v;
            } else {  // MODE 4
                v *= rsum[row];
                ((__bf16*)out)[sO*bz + (size_t)gi*ldo + gj] = (__bf16)v;
            }
        }
    }
}

extern "C" void kernel_launch(void* const* d_in, const int* in_sizes, int n_in,
                              void* d_out, int out_size, void* d_ws, size_t ws_size,
                              hipStream_t stream) {
    const float* x      = (const float*)d_in[0];
    const float* gn_w   = (const float*)d_in[1];
    const float* gn_b   = (const float*)d_in[2];
    const float* qkv_w  = (const float*)d_in[3];
    const float* qkv_b  = (const float*)d_in[4];
    const float* proj_w = (const float*)d_in[5];
    const float* proj_b = (const float*)d_in[6];

    char* w8 = (char*)d_ws;
    __bf16* qkT  = (__bf16*)(w8);                 // 32 MB  [B][4096][1024]
    __bf16* Vbuf = (__bf16*)(w8 + 33554432);      // 16 MB  [B][512][4096]
    __bf16* OT   = (__bf16*)(w8 + 50331648);      // 16 MB  [B][4096][512]
    __bf16* wq   = (__bf16*)(w8 + 67108864);      // 1.5 MB [1536][512]
    __bf16* pw   = (__bf16*)(w8 + 68681728);      // 0.5 MB [512][512]
    float*  rowpart = (float*)(w8 + 69206016);    // 2 MB   [4][32][4096]
    float*  st   = (float*)(w8 + 71303168);       // stats (256 B)
    const size_t baseP = 71303424ULL;
    __bf16* hT   = (__bf16*)(w8 + baseP);         // 16 MB [B][4096][512] (dead after QKV)
    __bf16* P    = (__bf16*)(w8 + baseP);         // P chunks alias hT

    // how many batches of P (33.5 MB each) fit in remaining workspace
    size_t avail = (ws_size > baseP) ? (ws_size - baseP) : 0;
    int cap = (int)(avail / 33554432ULL);
    if (cap < 1) cap = 1;   // ws >= 134 MB established in round 1
    if (cap > 4) cap = 4;

    wconv<<<768, 256, 0, stream>>>(qkv_w, wq, 1536*512);
    wconv<<<256, 256, 0, stream>>>(proj_w, pw, 512*512);
    gn_stats<<<32, 256, 0, stream>>>(x, st);
    gn_apply_t<<<dim3(64, 8, 4), 256, 0, stream>>>(x, st, gn_w, gn_b, hT);

    // qkT[b][n][o] = sum_c hT[b][n][c]*qkv_w[o][c] + qkv_b[o], o in [0,1024)
    mm128<0><<<dim3(8, 32, 4), 512, 0, stream>>>(
        hT, 512, (size_t)4096*512, wq, 512, 0, 512,
        qkv_b, nullptr, 0, qkT, 1024, (size_t)4096*1024, nullptr);
    // V[b][o][n] = sum_c qkv_w[1024+o][c]*hT[b][n][c] + qkv_b[1024+o]
    mm128<1><<<dim3(32, 4, 4), 512, 0, stream>>>(
        wq + (size_t)1024*512, 512, 0, hT, 512, (size_t)4096*512, 512,
        qkv_b + 1024, nullptr, 0, Vbuf, 4096, (size_t)512*4096, nullptr);

    for (int b0 = 0; b0 < 4; b0 += cap) {
        int c = (4 - b0 < cap) ? (4 - b0) : cap;
        // P[z][q][key] = exp(SCALE * sum_c Q[q][c]K[key][c]); rowpart written
        mm128<3><<<dim3(32, 32, c), 512, 0, stream>>>(
            qkT + (size_t)b0*4194304, 1024, (size_t)4096*1024,
            qkT + (size_t)b0*4194304 + 512, 1024, (size_t)4096*1024, 512,
            nullptr, nullptr, 0, P, 4096, (size_t)4096*4096,
            rowpart + (size_t)b0*131072);
        // OT[z][q][c] = (sum_key P[q][key]V[c][key]) / rowsum[q]
        mm128<4><<<dim3(4, 32, c), 512, 0, stream>>>(
            P, 4096, (size_t)4096*4096,
            Vbuf + (size_t)b0*2097152, 4096, (size_t)512*4096, 4096,
            nullptr, nullptr, 0, OT + (size_t)b0*2097152, 512, (size_t)4096*512,
            rowpart + (size_t)b0*131072);
    }

    // out[b][co][n] = x + sum_c proj_w[co][c]*OT[b][n][c] + proj_b[co]
    mm128<2><<<dim3(32, 4, 4), 512, 0, stream>>>(
        pw, 512, 0, OT, 512, (size_t)4096*512, 512,
        proj_b, x, (size_t)512*4096, (float*)d_out, 4096, (size_t)512*4096, nullptr);
}

// Round 5
// 330.059 us; speedup vs baseline: 19.7260x; 1.2157x over previous
//
#include <hip/hip_runtime.h>
#include <math.h>

#define SCALE 0.044194173824159216f  // 512^-0.5

typedef __bf16 bf16x8 __attribute__((ext_vector_type(8)));
typedef float  f32x16 __attribute__((ext_vector_type(16)));
typedef unsigned int u32;

__device__ __forceinline__ void gload16(const void* g, void* l) {
    __builtin_amdgcn_global_load_lds(
        (const __attribute__((address_space(1))) u32*)g,
        (__attribute__((address_space(3))) u32*)l, 16, 0, 0);
}

// ---------------------------------------------------------------- GroupNorm stats (2-stage)
__global__ __launch_bounds__(256) void gn_part(const float* __restrict__ x,
                                               float* __restrict__ part) {
    int gi = blockIdx.x >> 3, sl = blockIdx.x & 7;   // gi = b*8+g
    const float4* p = (const float4*)(x + (size_t)gi * 64 * 4096) + (size_t)sl * 8192;
    float s = 0.f, ss = 0.f;
    #pragma unroll 4
    for (int i = threadIdx.x; i < 8192; i += 256) {
        float4 v = p[i];
        s  += v.x + v.y + v.z + v.w;
        ss += v.x*v.x + v.y*v.y + v.z*v.z + v.w*v.w;
    }
    __shared__ float rs[256], rss[256];
    rs[threadIdx.x] = s; rss[threadIdx.x] = ss;
    __syncthreads();
    for (int o = 128; o > 0; o >>= 1) {
        if (threadIdx.x < o) { rs[threadIdx.x] += rs[threadIdx.x+o]; rss[threadIdx.x] += rss[threadIdx.x+o]; }
        __syncthreads();
    }
    if (threadIdx.x == 0) {
        part[blockIdx.x*2 + 0] = rs[0];
        part[blockIdx.x*2 + 1] = rss[0];
    }
}

__global__ __launch_bounds__(64) void gn_fin(const float* __restrict__ part,
                                             float* __restrict__ stats) {
    int t = threadIdx.x;
    if (t < 32) {
        float s = 0.f, ss = 0.f;
        #pragma unroll
        for (int i = 0; i < 8; ++i) { s += part[(t*8+i)*2]; ss += part[(t*8+i)*2+1]; }
        float inv = 1.0f / (float)(64 * 4096);
        float mu  = s * inv;
        float var = ss * inv - mu * mu;
        stats[t*2 + 0] = mu;
        stats[t*2 + 1] = rsqrtf(var + 1e-5f);
    }
}

// --------------------------------------- GN apply + transpose -> hT [B][4096][512] bf16
__global__ __launch_bounds__(256) void gn_apply_t(const float* __restrict__ x,
                                                  const float* __restrict__ stats,
                                                  const float* __restrict__ gw,
                                                  const float* __restrict__ gb,
                                                  __bf16* __restrict__ hT) {
    __shared__ __bf16 tile[64][88];   // 176B pitch: 16B-aligned rows
    int b = blockIdx.z, c0 = blockIdx.y * 64, n0 = blockIdx.x * 64;
    int t = threadIdx.x;
    float mu  = stats[(b*8 + blockIdx.y)*2];
    float rsg = stats[(b*8 + blockIdx.y)*2 + 1];
    int c = t >> 2, ns = t & 3;
    float a = gw[c0+c] * rsg;
    float d = gb[c0+c] - mu * a;
    const float* xr = x + ((size_t)b*512 + c0 + c)*4096 + n0 + ns*16;
    #pragma unroll
    for (int e4 = 0; e4 < 4; ++e4) {
        float4 v = *(const float4*)(xr + e4*4);
        tile[ns*16 + e4*4 + 0][c] = (__bf16)(v.x*a + d);
        tile[ns*16 + e4*4 + 1][c] = (__bf16)(v.y*a + d);
        tile[ns*16 + e4*4 + 2][c] = (__bf16)(v.z*a + d);
        tile[ns*16 + e4*4 + 3][c] = (__bf16)(v.w*a + d);
    }
    __syncthreads();
    int n = t >> 2, cs = t & 3;
    __bf16* dst = hT + ((size_t)b*4096 + n0 + n)*512 + c0 + cs*16;
    *(uint4*)(dst)     = *(const uint4*)(&tile[n][cs*16]);
    *(uint4*)(dst + 8) = *(const uint4*)(&tile[n][cs*16 + 8]);
}

// ---------------------------------------------------------------- weight f32->bf16
__global__ __launch_bounds__(256) void wconv(const float* __restrict__ src,
                                             __bf16* __restrict__ dst, int n) {
    int i = (blockIdx.x*256 + threadIdx.x) * 4;
    if (i < n) {
        float4 v = *(const float4*)(src + i);
        dst[i+0] = (__bf16)v.x; dst[i+1] = (__bf16)v.y;
        dst[i+2] = (__bf16)v.z; dst[i+3] = (__bf16)v.w;
    }
}

// ---------------------------------------------------------------- 128x128 MFMA GEMM
// D[i][j] = sum_k A[i][k]*B[j][k]; A,B bf16 row-major, k contiguous.
// Staging: global_load_lds width=16, linear LDS dest, XOR-swizzle on the
// per-lane GLOBAL source address; ds_read side uses the same swizzle.
// MODE 0: +bias[j], bf16 out                   (QKV -> qkT)
// MODE 1: +bias[i], bf16 out                   (V)
// MODE 2: +bias[i]+res, f32 out                (proj + residual)
// MODE 3: exp(acc*SCALE) -> bf16 P + rowpart   (S-GEMM)
// MODE 4: acc * 1/rowsum -> bf16 out           (PV-GEMM)
template<int MODE>
__global__ __launch_bounds__(512) void mm128(
        const __bf16* __restrict__ A, int lda, size_t sA,
        const __bf16* __restrict__ B, int ldb, size_t sB,
        int Kdim,
        const float* __restrict__ bias,
        const float* __restrict__ res, size_t sR,
        void* __restrict__ out, int ldo, size_t sO,
        float* __restrict__ rowpart) {
    __shared__ __bf16 As[2][128][64];
    __shared__ __bf16 Bs[2][128][64];
    __shared__ float  redp[128*4];    // MODE 3 cross-wave rowsum partials
    __shared__ float  rsum[128];      // MODE 4 1/rowsum

    const int t = threadIdx.x, w = t >> 6, l = t & 63;
    const int l31 = l & 31, lh = l >> 5;
    const int j0 = blockIdx.x*128, i0 = blockIdx.y*128, bz = blockIdx.z;
    const __bf16* Ab = A + sA * bz;
    const __bf16* Bb = B + sB * bz;
    const int iw = w & 1, jw = w >> 1;

    if constexpr (MODE == 4) {
        if (t < 128) {
            const float* rp = rowpart + (size_t)bz*131072 + i0 + t;
            float s = 0.f;
            #pragma unroll
            for (int jb = 0; jb < 32; ++jb) s += rp[jb*4096];
            rsum[t] = 1.0f / s;
        }
    }

    // staging geometry: slot s in [0,1024) covers tile (row = s>>3, 16B-col = s&7).
    // wave w, issue i: slots [i*512 + w*64, +64); lane l -> slot base+l (linear LDS).
    // global col slot is XOR-swizzled so LDS slot s holds global col (s&7)^(row&7).
    const int s0 = w*64 + l;               // issue 0 slot
    const int rowS0 = s0 >> 3;
    const int csS0  = (s0 & 7) ^ (rowS0 & 7);
    const int rowS1 = rowS0 + 64;          // issue 1 slot = s0 + 512
    const int csS1  = (s0 & 7) ^ (rowS1 & 7);
    const int ldsOff0 = (w*64) * 16;       // wave-uniform LDS byte base, issue 0
    const int ldsOff1 = (512 + w*64) * 16; // issue 1

    f32x16 acc[2];
    #pragma unroll
    for (int i = 0; i < 2; ++i)
        #pragma unroll
        for (int r = 0; r < 16; ++r) acc[i][r] = 0.f;

    // prologue: stage chunk 0 into buf 0
    gload16(Ab + (size_t)(i0 + rowS0)*lda + csS0*8, (char*)&As[0][0][0] + ldsOff0);
    gload16(Ab + (size_t)(i0 + rowS1)*lda + csS1*8, (char*)&As[0][0][0] + ldsOff1);
    gload16(Bb + (size_t)(j0 + rowS0)*ldb + csS0*8, (char*)&Bs[0][0][0] + ldsOff0);
    gload16(Bb + (size_t)(j0 + rowS1)*ldb + csS1*8, (char*)&Bs[0][0][0] + ldsOff1);
    __syncthreads();

    const int nch = Kdim >> 6;
    for (int cc = 0; cc < nch; ++cc) {
        if (cc + 1 < nch) {
            int c0 = (cc + 1) * 64;
            char* An = (char*)&As[(cc + 1) & 1][0][0];
            char* Bn = (char*)&Bs[(cc + 1) & 1][0][0];
            gload16(Ab + (size_t)(i0 + rowS0)*lda + c0 + csS0*8, An + ldsOff0);
            gload16(Ab + (size_t)(i0 + rowS1)*lda + c0 + csS1*8, An + ldsOff1);
            gload16(Bb + (size_t)(j0 + rowS0)*ldb + c0 + csS0*8, Bn + ldsOff0);
            gload16(Bb + (size_t)(j0 + rowS1)*ldb + c0 + csS1*8, Bn + ldsOff1);
        }
        const char* Ac = (const char*)&As[cc & 1][0][0];
        const char* Bc = (const char*)&Bs[cc & 1][0][0];
        #pragma unroll
        for (int ks = 0; ks < 4; ++ks) {
            int brow = jw*32 + l31;
            int bs = (2*ks + lh) ^ (brow & 7);
            bf16x8 bf = *(const bf16x8*)(Bc + brow*128 + bs*16);
            #pragma unroll
            for (int tt = 0; tt < 2; ++tt) {
                int arow = iw*64 + tt*32 + l31;
                int as = (2*ks + lh) ^ (arow & 7);
                bf16x8 af = *(const bf16x8*)(Ac + arow*128 + as*16);
                acc[tt] = __builtin_amdgcn_mfma_f32_32x32x16_bf16(af, bf, acc[tt], 0, 0, 0);
            }
        }
        __syncthreads();   // drains vmcnt: next-chunk LDS ready; buf reuse safe
    }

    const int gj = j0 + jw*32 + l31;

    if constexpr (MODE == 3) {
        // exp + store P + rowsum partials (no atomics)
        #pragma unroll
        for (int tt = 0; tt < 2; ++tt) {
            float es[16];
            #pragma unroll
            for (int r = 0; r < 16; ++r) {
                float e = __expf(acc[tt][r] * SCALE);
                es[r] = e;
                int row = iw*64 + tt*32 + (r & 3) + 8*(r >> 2) + 4*lh;
                ((__bf16*)out)[sO*bz + (size_t)(i0 + row)*ldo + gj] = (__bf16)e;
            }
            #pragma unroll
            for (int m = 1; m < 32; m <<= 1)
                #pragma unroll
                for (int r = 0; r < 16; ++r) es[r] += __shfl_xor(es[r], m);
            if (l31 == 0) {
                #pragma unroll
                for (int r = 0; r < 16; ++r) {
                    int row = iw*64 + tt*32 + (r & 3) + 8*(r >> 2) + 4*lh;
                    redp[row*4 + jw] = es[r];
                }
            }
        }
        __syncthreads();
        if (t < 128) {
            float s = redp[t*4+0] + redp[t*4+1] + redp[t*4+2] + redp[t*4+3];
            rowpart[(size_t)bz*131072 + (size_t)blockIdx.x*4096 + i0 + t] = s;
        }
        return;
    }

    float bcol = (MODE == 0) ? bias[gj] : 0.f;
    #pragma unroll
    for (int tt = 0; tt < 2; ++tt) {
        #pragma unroll
        for (int r = 0; r < 16; ++r) {
            int row = iw*64 + tt*32 + (r & 3) + 8*(r >> 2) + 4*lh;
            int gi = i0 + row;
            float v = acc[tt][r];
            if constexpr (MODE == 0) {
                v += bcol;
                ((__bf16*)out)[sO*bz + (size_t)gi*ldo + gj] = (__bf16)v;
            } else if constexpr (MODE == 1) {
                v += bias[gi];
                ((__bf16*)out)[sO*bz + (size_t)gi*ldo + gj] = (__bf16)v;
            } else if constexpr (MODE == 2) {
                v += bias[gi] + res[sR*bz + (size_t)gi*ldo + gj];
                ((float*)out)[sO*bz + (size_t)gi*ldo + gj] = v;
            } else {  // MODE 4
                v *= rsum[row];
                ((__bf16*)out)[sO*bz + (size_t)gi*ldo + gj] = (__bf16)v;
            }
        }
    }
}

extern "C" void kernel_launch(void* const* d_in, const int* in_sizes, int n_in,
                              void* d_out, int out_size, void* d_ws, size_t ws_size,
                              hipStream_t stream) {
    const float* x      = (const float*)d_in[0];
    const float* gn_w   = (const float*)d_in[1];
    const float* gn_b   = (const float*)d_in[2];
    const float* qkv_w  = (const float*)d_in[3];
    const float* qkv_b  = (const float*)d_in[4];
    const float* proj_w = (const float*)d_in[5];
    const float* proj_b = (const float*)d_in[6];

    char* w8 = (char*)d_ws;
    __bf16* qkT  = (__bf16*)(w8);                 // 32 MB  [B][4096][1024]
    __bf16* Vbuf = (__bf16*)(w8 + 33554432);      // 16 MB  [B][512][4096]
    __bf16* OT   = (__bf16*)(w8 + 50331648);      // 16 MB  [B][4096][512]
    __bf16* wq   = (__bf16*)(w8 + 67108864);      // 1.5 MB [1536][512]
    __bf16* pw   = (__bf16*)(w8 + 68681728);      // 0.5 MB [512][512]
    float*  rowpart = (float*)(w8 + 69206016);    // 2 MB   [4][32][4096]
    float*  part = (float*)(w8 + 71303168);       // 2 KB gn partials
    float*  st   = (float*)(w8 + 71305216);       // 256 B stats
    const size_t baseP = 71305472ULL;
    __bf16* hT   = (__bf16*)(w8 + baseP);         // 16 MB [B][4096][512] (dead after QKV)
    __bf16* P    = (__bf16*)(w8 + baseP);         // P chunks alias hT

    size_t avail = (ws_size > baseP) ? (ws_size - baseP) : 0;
    int cap = (int)(avail / 33554432ULL);
    if (cap < 1) cap = 1;
    if (cap > 4) cap = 4;

    wconv<<<768, 256, 0, stream>>>(qkv_w, wq, 1536*512);
    wconv<<<256, 256, 0, stream>>>(proj_w, pw, 512*512);
    gn_part<<<256, 256, 0, stream>>>(x, part);
    gn_fin<<<1, 64, 0, stream>>>(part, st);
    gn_apply_t<<<dim3(64, 8, 4), 256, 0, stream>>>(x, st, gn_w, gn_b, hT);

    // qkT[b][n][o] = sum_c hT[b][n][c]*qkv_w[o][c] + qkv_b[o], o in [0,1024)
    mm128<0><<<dim3(8, 32, 4), 512, 0, stream>>>(
        hT, 512, (size_t)4096*512, wq, 512, 0, 512,
        qkv_b, nullptr, 0, qkT, 1024, (size_t)4096*1024, nullptr);
    // V[b][o][n] = sum_c qkv_w[1024+o][c]*hT[b][n][c] + qkv_b[1024+o]
    mm128<1><<<dim3(32, 4, 4), 512, 0, stream>>>(
        wq + (size_t)1024*512, 512, 0, hT, 512, (size_t)4096*512, 512,
        qkv_b + 1024, nullptr, 0, Vbuf, 4096, (size_t)512*4096, nullptr);

    for (int b0 = 0; b0 < 4; b0 += cap) {
        int c = (4 - b0 < cap) ? (4 - b0) : cap;
        // P[z][q][key] = exp(SCALE * sum_c Q[q][c]K[key][c]); rowpart written
        mm128<3><<<dim3(32, 32, c), 512, 0, stream>>>(
            qkT + (size_t)b0*4194304, 1024, (size_t)4096*1024,
            qkT + (size_t)b0*4194304 + 512, 1024, (size_t)4096*1024, 512,
            nullptr, nullptr, 0, P, 4096, (size_t)4096*4096,
            rowpart + (size_t)b0*131072);
        // OT[z][q][c] = (sum_key P[q][key]V[c][key]) / rowsum[q]
        mm128<4><<<dim3(4, 32, c), 512, 0, stream>>>(
            P, 4096, (size_t)4096*4096,
            Vbuf + (size_t)b0*2097152, 4096, (size_t)512*4096, 4096,
            nullptr, nullptr, 0, OT + (size_t)b0*2097152, 512, (size_t)4096*512,
            rowpart + (size_t)b0*131072);
    }

    // out[b][co][n] = x + sum_c proj_w[co][c]*OT[b][n][c] + proj_b[co]
    mm128<2><<<dim3(32, 4, 4), 512, 0, stream>>>(
        pw, 512, 0, OT, 512, (size_t)4096*512, 512,
        proj_b, x, (size_t)512*4096, (float*)d_out, 4096, (size_t)512*4096, nullptr);
}

// Round 6
// 304.362 us; speedup vs baseline: 21.3914x; 1.0844x over previous
//
#include <hip/hip_runtime.h>
#include <math.h>

#define SCALE 0.044194173824159216f  // 512^-0.5

typedef __bf16 bf16x8 __attribute__((ext_vector_type(8)));
typedef float  f32x4  __attribute__((ext_vector_type(4)));
typedef unsigned int u32;

__device__ __forceinline__ void gload16(const void* g, void* l) {
    __builtin_amdgcn_global_load_lds(
        (const __attribute__((address_space(1))) u32*)g,
        (__attribute__((address_space(3))) u32*)l, 16, 0, 0);
}

// ---------------------------------------------------------------- GroupNorm stats (2-stage)
__global__ __launch_bounds__(256) void gn_part(const float* __restrict__ x,
                                               float* __restrict__ part) {
    int gi = blockIdx.x >> 3, sl = blockIdx.x & 7;   // gi = b*8+g
    const float4* p = (const float4*)(x + (size_t)gi * 64 * 4096) + (size_t)sl * 8192;
    float s = 0.f, ss = 0.f;
    #pragma unroll 4
    for (int i = threadIdx.x; i < 8192; i += 256) {
        float4 v = p[i];
        s  += v.x + v.y + v.z + v.w;
        ss += v.x*v.x + v.y*v.y + v.z*v.z + v.w*v.w;
    }
    __shared__ float rs[256], rss[256];
    rs[threadIdx.x] = s; rss[threadIdx.x] = ss;
    __syncthreads();
    for (int o = 128; o > 0; o >>= 1) {
        if (threadIdx.x < o) { rs[threadIdx.x] += rs[threadIdx.x+o]; rss[threadIdx.x] += rss[threadIdx.x+o]; }
        __syncthreads();
    }
    if (threadIdx.x == 0) {
        part[blockIdx.x*2 + 0] = rs[0];
        part[blockIdx.x*2 + 1] = rss[0];
    }
}

__global__ __launch_bounds__(64) void gn_fin(const float* __restrict__ part,
                                             float* __restrict__ stats) {
    int t = threadIdx.x;
    if (t < 32) {
        float s = 0.f, ss = 0.f;
        #pragma unroll
        for (int i = 0; i < 8; ++i) { s += part[(t*8+i)*2]; ss += part[(t*8+i)*2+1]; }
        float inv = 1.0f / (float)(64 * 4096);
        float mu  = s * inv;
        float var = ss * inv - mu * mu;
        stats[t*2 + 0] = mu;
        stats[t*2 + 1] = rsqrtf(var + 1e-5f);
    }
}

// --------------------------------------- GN apply + transpose -> hT [B][4096][512] bf16
__global__ __launch_bounds__(256) void gn_apply_t(const float* __restrict__ x,
                                                  const float* __restrict__ stats,
                                                  const float* __restrict__ gw,
                                                  const float* __restrict__ gb,
                                                  __bf16* __restrict__ hT) {
    __shared__ __bf16 tile[64][88];   // 176B pitch: 16B-aligned rows
    int b = blockIdx.z, c0 = blockIdx.y * 64, n0 = blockIdx.x * 64;
    int t = threadIdx.x;
    float mu  = stats[(b*8 + blockIdx.y)*2];
    float rsg = stats[(b*8 + blockIdx.y)*2 + 1];
    int c = t >> 2, ns = t & 3;
    float a = gw[c0+c] * rsg;
    float d = gb[c0+c] - mu * a;
    const float* xr = x + ((size_t)b*512 + c0 + c)*4096 + n0 + ns*16;
    #pragma unroll
    for (int e4 = 0; e4 < 4; ++e4) {
        float4 v = *(const float4*)(xr + e4*4);
        tile[ns*16 + e4*4 + 0][c] = (__bf16)(v.x*a + d);
        tile[ns*16 + e4*4 + 1][c] = (__bf16)(v.y*a + d);
        tile[ns*16 + e4*4 + 2][c] = (__bf16)(v.z*a + d);
        tile[ns*16 + e4*4 + 3][c] = (__bf16)(v.w*a + d);
    }
    __syncthreads();
    int n = t >> 2, cs = t & 3;
    __bf16* dst = hT + ((size_t)b*4096 + n0 + n)*512 + c0 + cs*16;
    *(uint4*)(dst)     = *(const uint4*)(&tile[n][cs*16]);
    *(uint4*)(dst + 8) = *(const uint4*)(&tile[n][cs*16 + 8]);
}

// ---------------------------------------------------------------- weight f32->bf16
__global__ __launch_bounds__(256) void wconv(const float* __restrict__ src,
                                             __bf16* __restrict__ dst, int n) {
    int i = (blockIdx.x*256 + threadIdx.x) * 4;
    if (i < n) {
        float4 v = *(const float4*)(src + i);
        dst[i+0] = (__bf16)v.x; dst[i+1] = (__bf16)v.y;
        dst[i+2] = (__bf16)v.z; dst[i+3] = (__bf16)v.w;
    }
}

// ---------------------------------------------------------------- 128x128 MFMA GEMM
// m97-structure: 256 thr / 4 waves, wave tile 64x64 = 4x4 accs of 16x16x32,
// BK=32, global_load_lds(16B) linear dest + XOR source-swizzle, 1 barrier/chunk.
// D[i][j] = sum_k A[i][k]*B[j][k]; A,B bf16 row-major, k contiguous.
// MODE 0: +bias[j], bf16 out                   (QKV -> qkT)
// MODE 1: +bias[i], bf16 out                   (V)
// MODE 2: +bias[i]+res, f32 out                (proj + residual)
// MODE 3: exp(acc*SCALE) -> bf16 P + rowpart   (S-GEMM)
// MODE 4: acc * 1/rowsum -> bf16 out           (PV-GEMM)
template<int MODE>
__global__ __launch_bounds__(256) void mm128(
        const __bf16* __restrict__ A, int lda, size_t sA,
        const __bf16* __restrict__ B, int ldb, size_t sB,
        int Kdim,
        const float* __restrict__ bias,
        const float* __restrict__ res, size_t sR,
        void* __restrict__ out, int ldo, size_t sO,
        float* __restrict__ rowpart) {
    __shared__ __bf16 As[2][128][32];   // 64B rows, 4 slots of 16B
    __shared__ __bf16 Bs[2][128][32];
    __shared__ float  redp[256];        // MODE 3: [128 rows][2 colwaves]
    __shared__ float  rsum[128];        // MODE 4: 1/rowsum

    const int t = threadIdx.x, w = t >> 6, l = t & 63;
    const int l15 = l & 15, lq = l >> 4;
    const int j0 = blockIdx.x*128, i0 = blockIdx.y*128, bz = blockIdx.z;
    const __bf16* Ab = A + sA*bz;
    const __bf16* Bb = B + sB*bz;
    const int rowblk = (w & 1)*64;      // wave's row sub-block
    const int colblk = (w >> 1)*64;     // wave's col sub-block

    if constexpr (MODE == 4) {
        if (t < 128) {
            const float* rp = rowpart + (size_t)bz*131072 + i0 + t;
            float s = 0.f;
            #pragma unroll
            for (int jb = 0; jb < 32; ++jb) s += rp[jb*4096];
            rsum[t] = 1.0f / s;
        }
    }

    // staging: 512 slots/array (row = slot>>2, 16B-slot = slot&3), 2 issues of 256.
    // LDS dest linear; global source pre-swizzled: slot s of row r holds
    // global k-slot s ^ ((r>>1)&3)  (involution; read side applies same XOR).
    const int slot0 = w*64 + l;
    const int rowS0 = slot0 >> 2;
    const int rowS1 = rowS0 + 64;
    const int csS   = (((slot0 & 3) ^ ((rowS0 >> 1) & 3))) * 8;  // element offset (16B slot)
    const int off0  = (w*64)*16;         // wave-uniform LDS byte base, issue 0
    const int off1  = (256 + w*64)*16;   // issue 1

    f32x4 acc[4][4];
    #pragma unroll
    for (int mr = 0; mr < 4; ++mr)
        #pragma unroll
        for (int nr = 0; nr < 4; ++nr)
            #pragma unroll
            for (int r = 0; r < 4; ++r) acc[mr][nr][r] = 0.f;

    auto STAGE = [&](int kc, int bi) {
        char* Ad = (char*)As[bi];
        char* Bd = (char*)Bs[bi];
        gload16(Ab + (size_t)(i0 + rowS0)*lda + kc + csS, Ad + off0);
        gload16(Ab + (size_t)(i0 + rowS1)*lda + kc + csS, Ad + off1);
        gload16(Bb + (size_t)(j0 + rowS0)*ldb + kc + csS, Bd + off0);
        gload16(Bb + (size_t)(j0 + rowS1)*ldb + kc + csS, Bd + off1);
    };

    const int rsw = (l15 >> 1) & 3;      // (row>>1)&3 contribution from l15
    const int koff = (lq ^ rsw) << 4;    // swizzled 16B slot offset for frag reads

    const int nch = Kdim >> 5;           // BK=32
    STAGE(0, 0);
    __syncthreads();

    for (int cc = 0; cc < nch; ++cc) {
        if (cc + 1 < nch) STAGE((cc + 1)*32, (cc + 1) & 1);
        const char* Ac = (const char*)As[cc & 1];
        const char* Bc = (const char*)Bs[cc & 1];
        bf16x8 av[4], bv[4];
        #pragma unroll
        for (int mr = 0; mr < 4; ++mr) {
            int row = rowblk + mr*16 + l15;
            av[mr] = *(const bf16x8*)(Ac + row*64 + koff);
        }
        #pragma unroll
        for (int nr = 0; nr < 4; ++nr) {
            int row = colblk + nr*16 + l15;
            bv[nr] = *(const bf16x8*)(Bc + row*64 + koff);
        }
        #pragma unroll
        for (int mr = 0; mr < 4; ++mr)
            #pragma unroll
            for (int nr = 0; nr < 4; ++nr)
                acc[mr][nr] = __builtin_amdgcn_mfma_f32_16x16x32_bf16(av[mr], bv[nr], acc[mr][nr], 0, 0, 0);
        __syncthreads();
    }

    if constexpr (MODE == 3) {
        float rpart[4][4];
        #pragma unroll
        for (int mr = 0; mr < 4; ++mr)
            #pragma unroll
            for (int r = 0; r < 4; ++r) rpart[mr][r] = 0.f;
        #pragma unroll
        for (int mr = 0; mr < 4; ++mr)
            #pragma unroll
            for (int nr = 0; nr < 4; ++nr) {
                int col = j0 + colblk + nr*16 + l15;
                #pragma unroll
                for (int r = 0; r < 4; ++r) {
                    int row = rowblk + mr*16 + lq*4 + r;
                    float e = __expf(acc[mr][nr][r] * SCALE);
                    ((__bf16*)out)[sO*bz + (size_t)(i0 + row)*ldo + col] = (__bf16)e;
                    rpart[mr][r] += e;
                }
            }
        #pragma unroll
        for (int m = 1; m < 16; m <<= 1)
            #pragma unroll
            for (int mr = 0; mr < 4; ++mr)
                #pragma unroll
                for (int r = 0; r < 4; ++r)
                    rpart[mr][r] += __shfl_xor(rpart[mr][r], m);
        if (l15 == 0) {
            #pragma unroll
            for (int mr = 0; mr < 4; ++mr)
                #pragma unroll
                for (int r = 0; r < 4; ++r)
                    redp[(rowblk + mr*16 + lq*4 + r)*2 + (w >> 1)] = rpart[mr][r];
        }
        __syncthreads();
        if (t < 128)
            rowpart[(size_t)bz*131072 + (size_t)blockIdx.x*4096 + i0 + t] =
                redp[t*2] + redp[t*2 + 1];
        return;
    }

    #pragma unroll
    for (int mr = 0; mr < 4; ++mr)
        #pragma unroll
        for (int nr = 0; nr < 4; ++nr) {
            int col = j0 + colblk + nr*16 + l15;
            #pragma unroll
            for (int r = 0; r < 4; ++r) {
                int lrow = rowblk + mr*16 + lq*4 + r;
                int gi = i0 + lrow;
                float v = acc[mr][nr][r];
                if constexpr (MODE == 0) {
                    v += bias[col];
                    ((__bf16*)out)[sO*bz + (size_t)gi*ldo + col] = (__bf16)v;
                } else if constexpr (MODE == 1) {
                    v += bias[gi];
                    ((__bf16*)out)[sO*bz + (size_t)gi*ldo + col] = (__bf16)v;
                } else if constexpr (MODE == 2) {
                    v += bias[gi] + res[sR*bz + (size_t)gi*ldo + col];
                    ((float*)out)[sO*bz + (size_t)gi*ldo + col] = v;
                } else {  // MODE 4
                    v *= rsum[lrow];
                    ((__bf16*)out)[sO*bz + (size_t)gi*ldo + col] = (__bf16)v;
                }
            }
        }
}

extern "C" void kernel_launch(void* const* d_in, const int* in_sizes, int n_in,
                              void* d_out, int out_size, void* d_ws, size_t ws_size,
                              hipStream_t stream) {
    const float* x      = (const float*)d_in[0];
    const float* gn_w   = (const float*)d_in[1];
    const float* gn_b   = (const float*)d_in[2];
    const float* qkv_w  = (const float*)d_in[3];
    const float* qkv_b  = (const float*)d_in[4];
    const float* proj_w = (const float*)d_in[5];
    const float* proj_b = (const float*)d_in[6];

    char* w8 = (char*)d_ws;
    __bf16* qkT  = (__bf16*)(w8);                 // 32 MB  [B][4096][1024]
    __bf16* Vbuf = (__bf16*)(w8 + 33554432);      // 16 MB  [B][512][4096]
    __bf16* OT   = (__bf16*)(w8 + 50331648);      // 16 MB  [B][4096][512]
    __bf16* wq   = (__bf16*)(w8 + 67108864);      // 1.5 MB [1536][512]
    __bf16* pw   = (__bf16*)(w8 + 68681728);      // 0.5 MB [512][512]
    float*  rowpart = (float*)(w8 + 69206016);    // 2 MB   [4][32][4096]
    float*  part = (float*)(w8 + 71303168);       // 2 KB gn partials
    float*  st   = (float*)(w8 + 71305216);       // 256 B stats
    const size_t baseP = 71305472ULL;
    __bf16* hT   = (__bf16*)(w8 + baseP);         // 16 MB [B][4096][512] (dead after QKV)
    __bf16* P    = (__bf16*)(w8 + baseP);         // P chunks alias hT

    size_t avail = (ws_size > baseP) ? (ws_size - baseP) : 0;
    int cap = (int)(avail / 33554432ULL);
    if (cap < 1) cap = 1;
    if (cap > 4) cap = 4;

    wconv<<<768, 256, 0, stream>>>(qkv_w, wq, 1536*512);
    wconv<<<256, 256, 0, stream>>>(proj_w, pw, 512*512);
    gn_part<<<256, 256, 0, stream>>>(x, part);
    gn_fin<<<1, 64, 0, stream>>>(part, st);
    gn_apply_t<<<dim3(64, 8, 4), 256, 0, stream>>>(x, st, gn_w, gn_b, hT);

    // qkT[b][n][o] = sum_c hT[b][n][c]*qkv_w[o][c] + qkv_b[o], o in [0,1024)
    mm128<0><<<dim3(8, 32, 4), 256, 0, stream>>>(
        hT, 512, (size_t)4096*512, wq, 512, 0, 512,
        qkv_b, nullptr, 0, qkT, 1024, (size_t)4096*1024, nullptr);
    // V[b][o][n] = sum_c qkv_w[1024+o][c]*hT[b][n][c] + qkv_b[1024+o]
    mm128<1><<<dim3(32, 4, 4), 256, 0, stream>>>(
        wq + (size_t)1024*512, 512, 0, hT, 512, (size_t)4096*512, 512,
        qkv_b + 1024, nullptr, 0, Vbuf, 4096, (size_t)512*4096, nullptr);

    for (int b0 = 0; b0 < 4; b0 += cap) {
        int c = (4 - b0 < cap) ? (4 - b0) : cap;
        // P[z][q][key] = exp(SCALE * sum_c Q[q][c]K[key][c]); rowpart written
        mm128<3><<<dim3(32, 32, c), 256, 0, stream>>>(
            qkT + (size_t)b0*4194304, 1024, (size_t)4096*1024,
            qkT + (size_t)b0*4194304 + 512, 1024, (size_t)4096*1024, 512,
            nullptr, nullptr, 0, P, 4096, (size_t)4096*4096,
            rowpart + (size_t)b0*131072);
        // OT[z][q][c] = (sum_key P[q][key]V[c][key]) / rowsum[q]
        mm128<4><<<dim3(4, 32, c), 256, 0, stream>>>(
            P, 4096, (size_t)4096*4096,
            Vbuf + (size_t)b0*2097152, 4096, (size_t)512*4096, 4096,
            nullptr, nullptr, 0, OT + (size_t)b0*2097152, 512, (size_t)4096*512,
            rowpart + (size_t)b0*131072);
    }

    // out[b][co][n] = x + sum_c proj_w[co][c]*OT[b][n][c] + proj_b[co]
    mm128<2><<<dim3(32, 4, 4), 256, 0, stream>>>(
        pw, 512, 0, OT, 512, (size_t)4096*512, 512,
        proj_b, x, (size_t)512*4096, (float*)d_out, 4096, (size_t)512*4096, nullptr);
}

// Round 7
// 303.313 us; speedup vs baseline: 21.4654x; 1.0035x over previous
//
#include <hip/hip_runtime.h>
#include <math.h>

#define SCALE 0.044194173824159216f  // 512^-0.5

typedef __bf16 bf16x8 __attribute__((ext_vector_type(8)));
typedef float  f32x4  __attribute__((ext_vector_type(4)));
typedef unsigned int u32;

__device__ __forceinline__ void gload16(const void* g, void* l) {
    __builtin_amdgcn_global_load_lds(
        (const __attribute__((address_space(1))) u32*)g,
        (__attribute__((address_space(3))) u32*)l, 16, 0, 0);
}

__device__ __forceinline__ float sum8bf(bf16x8 v) {
    float s = 0.f;
    #pragma unroll
    for (int i = 0; i < 8; ++i) s += (float)v[i];
    return s;
}

// ---------------------------------------------------------------- GroupNorm stats (2-stage)
__global__ __launch_bounds__(256) void gn_part(const float* __restrict__ x,
                                               float* __restrict__ part) {
    int gi = blockIdx.x >> 4, sl = blockIdx.x & 15;   // gi = b*8+g
    const float4* p = (const float4*)(x + (size_t)gi * 64 * 4096) + (size_t)sl * 4096;
    float s = 0.f, ss = 0.f;
    #pragma unroll 4
    for (int i = threadIdx.x; i < 4096; i += 256) {
        float4 v = p[i];
        s  += v.x + v.y + v.z + v.w;
        ss += v.x*v.x + v.y*v.y + v.z*v.z + v.w*v.w;
    }
    __shared__ float rs[256], rss[256];
    rs[threadIdx.x] = s; rss[threadIdx.x] = ss;
    __syncthreads();
    for (int o = 128; o > 0; o >>= 1) {
        if (threadIdx.x < o) { rs[threadIdx.x] += rs[threadIdx.x+o]; rss[threadIdx.x] += rss[threadIdx.x+o]; }
        __syncthreads();
    }
    if (threadIdx.x == 0) {
        part[blockIdx.x*2 + 0] = rs[0];
        part[blockIdx.x*2 + 1] = rss[0];
    }
}

__global__ __launch_bounds__(64) void gn_fin(const float* __restrict__ part,
                                             float* __restrict__ stats) {
    int t = threadIdx.x;
    if (t < 32) {
        float s = 0.f, ss = 0.f;
        #pragma unroll
        for (int i = 0; i < 16; ++i) { s += part[(t*16+i)*2]; ss += part[(t*16+i)*2+1]; }
        float inv = 1.0f / (float)(64 * 4096);
        float mu  = s * inv;
        float var = ss * inv - mu * mu;
        stats[t*2 + 0] = mu;
        stats[t*2 + 1] = rsqrtf(var + 1e-5f);
    }
}

// --------------------------------------- GN apply + transpose -> hT [B][4096][512] bf16
__global__ __launch_bounds__(256) void gn_apply_t(const float* __restrict__ x,
                                                  const float* __restrict__ stats,
                                                  const float* __restrict__ gw,
                                                  const float* __restrict__ gb,
                                                  __bf16* __restrict__ hT) {
    __shared__ __bf16 tile[64][88];   // 176B pitch: 16B-aligned rows
    int b = blockIdx.z, c0 = blockIdx.y * 64, n0 = blockIdx.x * 64;
    int t = threadIdx.x;
    float mu  = stats[(b*8 + blockIdx.y)*2];
    float rsg = stats[(b*8 + blockIdx.y)*2 + 1];
    int c = t >> 2, ns = t & 3;
    float a = gw[c0+c] * rsg;
    float d = gb[c0+c] - mu * a;
    const float* xr = x + ((size_t)b*512 + c0 + c)*4096 + n0 + ns*16;
    #pragma unroll
    for (int e4 = 0; e4 < 4; ++e4) {
        float4 v = *(const float4*)(xr + e4*4);
        tile[ns*16 + e4*4 + 0][c] = (__bf16)(v.x*a + d);
        tile[ns*16 + e4*4 + 1][c] = (__bf16)(v.y*a + d);
        tile[ns*16 + e4*4 + 2][c] = (__bf16)(v.z*a + d);
        tile[ns*16 + e4*4 + 3][c] = (__bf16)(v.w*a + d);
    }
    __syncthreads();
    int n = t >> 2, cs = t & 3;
    __bf16* dst = hT + ((size_t)b*4096 + n0 + n)*512 + c0 + cs*16;
    *(uint4*)(dst)     = *(const uint4*)(&tile[n][cs*16]);
    *(uint4*)(dst + 8) = *(const uint4*)(&tile[n][cs*16 + 8]);
}

// ---------------------------------------------------------------- weight f32->bf16
__global__ __launch_bounds__(256) void wconv(const float* __restrict__ src,
                                             __bf16* __restrict__ dst, int n) {
    int i = (blockIdx.x*256 + threadIdx.x) * 4;
    if (i < n) {
        float4 v = *(const float4*)(src + i);
        dst[i+0] = (__bf16)v.x; dst[i+1] = (__bf16)v.y;
        dst[i+2] = (__bf16)v.z; dst[i+3] = (__bf16)v.w;
    }
}

// ---------------------------------------------------------------- 128x128 MFMA GEMM
// m97-structure: 256 thr / 4 waves, wave tile 64x64 = 4x4 accs of 16x16x32,
// BK=32, global_load_lds(16B) linear dest + XOR source-swizzle, 1 barrier/chunk.
// XCD-chunked block swizzle (bijective, m204) for L2 panel reuse.
// D[i][j] = sum_k A[i][k]*B[j][k]; A,B bf16 row-major, k contiguous.
// MODE 0: +bias[j], bf16 out                   (QKV -> qkT)
// MODE 1: +bias[i], bf16 out                   (V)
// MODE 2: +bias[i]+res, f32 out                (proj + residual)
// MODE 3: exp(acc*SCALE) -> bf16 P             (S-GEMM, no reductions)
// MODE 4: in-loop rowsum of A; acc/rowsum out  (PV-GEMM)
template<int MODE>
__global__ __launch_bounds__(256) void mm128(
        const __bf16* __restrict__ A, int lda, size_t sA,
        const __bf16* __restrict__ B, int ldb, size_t sB,
        int Kdim,
        const float* __restrict__ bias,
        const float* __restrict__ res, size_t sR,
        void* __restrict__ out, int ldo, size_t sO) {
    __shared__ __bf16 As[2][128][32];   // 64B rows, 4 slots of 16B
    __shared__ __bf16 Bs[2][128][32];
    __shared__ float  rsum[128];        // MODE 4: 1/rowsum

    const int t = threadIdx.x, w = t >> 6, l = t & 63;
    const int l15 = l & 15, lq = l >> 4;
    const int bz = blockIdx.z;

    // XCD-chunked bijective swizzle of the (x,y) block index
    const int gx = gridDim.x;
    int lin = blockIdx.y * gx + blockIdx.x;
    {
        const int nwg = gx * gridDim.y;
        const int qn = nwg >> 3, rn = nwg & 7;
        const int xcd = lin & 7, idx = lin >> 3;
        const int base = (xcd < rn) ? xcd*(qn+1) : rn*(qn+1) + (xcd-rn)*qn;
        lin = base + idx;
    }
    const int j0 = (lin % gx) * 128;
    const int i0 = (lin / gx) * 128;

    const __bf16* Ab = A + sA*bz;
    const __bf16* Bb = B + sB*bz;
    const int rowblk = (w & 1)*64;      // wave's row sub-block
    const int colblk = (w >> 1)*64;     // wave's col sub-block

    // staging: 512 slots/array (row = slot>>2, 16B-slot = slot&3), 2 issues of 256.
    // LDS dest linear; global source pre-swizzled (involution slot^((row>>1)&3)).
    const int slot0 = w*64 + l;
    const int rowS0 = slot0 >> 2;
    const int rowS1 = rowS0 + 64;
    const int csS   = (((slot0 & 3) ^ ((rowS0 >> 1) & 3))) * 8;
    const int off0  = (w*64)*16;
    const int off1  = (256 + w*64)*16;

    f32x4 acc[4][4];
    #pragma unroll
    for (int mr = 0; mr < 4; ++mr)
        #pragma unroll
        for (int nr = 0; nr < 4; ++nr)
            #pragma unroll
            for (int r = 0; r < 4; ++r) acc[mr][nr][r] = 0.f;

    float rsacc[4] = {0.f, 0.f, 0.f, 0.f};

    auto STAGE = [&](int kc, int bi) {
        char* Ad = (char*)As[bi];
        char* Bd = (char*)Bs[bi];
        gload16(Ab + (size_t)(i0 + rowS0)*lda + kc + csS, Ad + off0);
        gload16(Ab + (size_t)(i0 + rowS1)*lda + kc + csS, Ad + off1);
        gload16(Bb + (size_t)(j0 + rowS0)*ldb + kc + csS, Bd + off0);
        gload16(Bb + (size_t)(j0 + rowS1)*ldb + kc + csS, Bd + off1);
    };

    const int rsw = (l15 >> 1) & 3;      // (row>>1)&3 contribution from l15
    const int koff = (lq ^ rsw) << 4;    // swizzled 16B slot offset for frag reads

    const int nch = Kdim >> 5;           // BK=32
    STAGE(0, 0);
    __syncthreads();

    for (int cc = 0; cc < nch; ++cc) {
        if (cc + 1 < nch) STAGE((cc + 1)*32, (cc + 1) & 1);
        const char* Ac = (const char*)As[cc & 1];
        const char* Bc = (const char*)Bs[cc & 1];
        bf16x8 av[4], bv[4];
        #pragma unroll
        for (int mr = 0; mr < 4; ++mr) {
            int row = rowblk + mr*16 + l15;
            av[mr] = *(const bf16x8*)(Ac + row*64 + koff);
        }
        #pragma unroll
        for (int nr = 0; nr < 4; ++nr) {
            int row = colblk + nr*16 + l15;
            bv[nr] = *(const bf16x8*)(Bc + row*64 + koff);
        }
        if constexpr (MODE == 4) {
            #pragma unroll
            for (int mr = 0; mr < 4; ++mr) rsacc[mr] += sum8bf(av[mr]);
        }
        #pragma unroll
        for (int mr = 0; mr < 4; ++mr)
            #pragma unroll
            for (int nr = 0; nr < 4; ++nr)
                acc[mr][nr] = __builtin_amdgcn_mfma_f32_16x16x32_bf16(av[mr], bv[nr], acc[mr][nr], 0, 0, 0);
        __syncthreads();
    }

    if constexpr (MODE == 4) {
        // reduce rowsum across the 4 lq lanes holding each A-row
        #pragma unroll
        for (int mr = 0; mr < 4; ++mr) {
            rsacc[mr] += __shfl_xor(rsacc[mr], 16);
            rsacc[mr] += __shfl_xor(rsacc[mr], 32);
        }
        if ((w >> 1) == 0 && lq == 0) {   // waves 0,1: rows 0..127
            #pragma unroll
            for (int mr = 0; mr < 4; ++mr)
                rsum[rowblk + mr*16 + l15] = 1.0f / rsacc[mr];
        }
        __syncthreads();
    }

    if constexpr (MODE == 3) {
        #pragma unroll
        for (int mr = 0; mr < 4; ++mr)
            #pragma unroll
            for (int nr = 0; nr < 4; ++nr) {
                int col = j0 + colblk + nr*16 + l15;
                #pragma unroll
                for (int r = 0; r < 4; ++r) {
                    int row = rowblk + mr*16 + lq*4 + r;
                    float e = __expf(acc[mr][nr][r] * SCALE);
                    ((__bf16*)out)[sO*bz + (size_t)(i0 + row)*ldo + col] = (__bf16)e;
                }
            }
        return;
    }

    #pragma unroll
    for (int mr = 0; mr < 4; ++mr)
        #pragma unroll
        for (int nr = 0; nr < 4; ++nr) {
            int col = j0 + colblk + nr*16 + l15;
            #pragma unroll
            for (int r = 0; r < 4; ++r) {
                int lrow = rowblk + mr*16 + lq*4 + r;
                int gi = i0 + lrow;
                float v = acc[mr][nr][r];
                if constexpr (MODE == 0) {
                    v += bias[col];
                    ((__bf16*)out)[sO*bz + (size_t)gi*ldo + col] = (__bf16)v;
                } else if constexpr (MODE == 1) {
                    v += bias[gi];
                    ((__bf16*)out)[sO*bz + (size_t)gi*ldo + col] = (__bf16)v;
                } else if constexpr (MODE == 2) {
                    v += bias[gi] + res[sR*bz + (size_t)gi*ldo + col];
                    ((float*)out)[sO*bz + (size_t)gi*ldo + col] = v;
                } else {  // MODE 4
                    v *= rsum[lrow];
                    ((__bf16*)out)[sO*bz + (size_t)gi*ldo + col] = (__bf16)v;
                }
            }
        }
}

extern "C" void kernel_launch(void* const* d_in, const int* in_sizes, int n_in,
                              void* d_out, int out_size, void* d_ws, size_t ws_size,
                              hipStream_t stream) {
    const float* x      = (const float*)d_in[0];
    const float* gn_w   = (const float*)d_in[1];
    const float* gn_b   = (const float*)d_in[2];
    const float* qkv_w  = (const float*)d_in[3];
    const float* qkv_b  = (const float*)d_in[4];
    const float* proj_w = (const float*)d_in[5];
    const float* proj_b = (const float*)d_in[6];

    char* w8 = (char*)d_ws;
    __bf16* qkT  = (__bf16*)(w8);                 // 32 MB  [B][4096][1024]
    __bf16* Vbuf = (__bf16*)(w8 + 33554432);      // 16 MB  [B][512][4096]
    __bf16* OT   = (__bf16*)(w8 + 50331648);      // 16 MB  [B][4096][512]
    __bf16* wq   = (__bf16*)(w8 + 67108864);      // 1.5 MB [1536][512]
    __bf16* pw   = (__bf16*)(w8 + 68681728);      // 0.5 MB [512][512]
    float*  part = (float*)(w8 + 69206016);       // 4 KB gn partials
    float*  st   = (float*)(w8 + 69210112);       // 256 B stats
    const size_t baseP = 69210368ULL;
    __bf16* hT   = (__bf16*)(w8 + baseP);         // 16 MB [B][4096][512] (dead after QKV)
    __bf16* P    = (__bf16*)(w8 + baseP);         // P chunks alias hT

    size_t avail = (ws_size > baseP) ? (ws_size - baseP) : 0;
    int cap = (int)(avail / 33554432ULL);
    if (cap < 1) cap = 1;
    if (cap > 4) cap = 4;

    wconv<<<768, 256, 0, stream>>>(qkv_w, wq, 1536*512);
    wconv<<<256, 256, 0, stream>>>(proj_w, pw, 512*512);
    gn_part<<<512, 256, 0, stream>>>(x, part);
    gn_fin<<<1, 64, 0, stream>>>(part, st);
    gn_apply_t<<<dim3(64, 8, 4), 256, 0, stream>>>(x, st, gn_w, gn_b, hT);

    // qkT[b][n][o] = sum_c hT[b][n][c]*qkv_w[o][c] + qkv_b[o], o in [0,1024)
    mm128<0><<<dim3(8, 32, 4), 256, 0, stream>>>(
        hT, 512, (size_t)4096*512, wq, 512, 0, 512,
        qkv_b, nullptr, 0, qkT, 1024, (size_t)4096*1024);
    // V[b][o][n] = sum_c qkv_w[1024+o][c]*hT[b][n][c] + qkv_b[1024+o]
    mm128<1><<<dim3(32, 4, 4), 256, 0, stream>>>(
        wq + (size_t)1024*512, 512, 0, hT, 512, (size_t)4096*512, 512,
        qkv_b + 1024, nullptr, 0, Vbuf, 4096, (size_t)512*4096);

    for (int b0 = 0; b0 < 4; b0 += cap) {
        int c = (4 - b0 < cap) ? (4 - b0) : cap;
        // P[z][q][key] = exp(SCALE * sum_c Q[q][c]K[key][c])
        mm128<3><<<dim3(32, 32, c), 256, 0, stream>>>(
            qkT + (size_t)b0*4194304, 1024, (size_t)4096*1024,
            qkT + (size_t)b0*4194304 + 512, 1024, (size_t)4096*1024, 512,
            nullptr, nullptr, 0, P, 4096, (size_t)4096*4096);
        // OT[z][q][c] = (sum_key P[q][key]V[c][key]) / rowsum[q]  (rowsum in-loop)
        mm128<4><<<dim3(4, 32, c), 256, 0, stream>>>(
            P, 4096, (size_t)4096*4096,
            Vbuf + (size_t)b0*2097152, 4096, (size_t)512*4096, 4096,
            nullptr, nullptr, 0, OT + (size_t)b0*2097152, 512, (size_t)4096*512);
    }

    // out[b][co][n] = x + sum_c proj_w[co][c]*OT[b][n][c] + proj_b[co]
    mm128<2><<<dim3(32, 4, 4), 256, 0, stream>>>(
        pw, 512, 0, OT, 512, (size_t)4096*512, 512,
        proj_b, x, (size_t)512*4096, (float*)d_out, 4096, (size_t)512*4096);
}

// Round 8
// 277.171 us; speedup vs baseline: 23.4900x; 1.0943x over previous
//
#include <hip/hip_runtime.h>
#include <math.h>

#define SCALE 0.044194173824159216f  // 512^-0.5

typedef __bf16 bf16x8 __attribute__((ext_vector_type(8)));
typedef float  f32x4  __attribute__((ext_vector_type(4)));
typedef unsigned int u32;

__device__ __forceinline__ void gload16(const void* g, void* l) {
    __builtin_amdgcn_global_load_lds(
        (const __attribute__((address_space(1))) u32*)g,
        (__attribute__((address_space(3))) u32*)l, 16, 0, 0);
}

// ---------------------------------------------------------------- GroupNorm stats (2-stage)
__global__ __launch_bounds__(256) void gn_part(const float* __restrict__ x,
                                               float* __restrict__ part) {
    int gi = blockIdx.x >> 4, sl = blockIdx.x & 15;   // gi = b*8+g
    const float4* p = (const float4*)(x + (size_t)gi * 64 * 4096) + (size_t)sl * 4096;
    float s = 0.f, ss = 0.f;
    #pragma unroll 4
    for (int i = threadIdx.x; i < 4096; i += 256) {
        float4 v = p[i];
        s  += v.x + v.y + v.z + v.w;
        ss += v.x*v.x + v.y*v.y + v.z*v.z + v.w*v.w;
    }
    __shared__ float rs[256], rss[256];
    rs[threadIdx.x] = s; rss[threadIdx.x] = ss;
    __syncthreads();
    for (int o = 128; o > 0; o >>= 1) {
        if (threadIdx.x < o) { rs[threadIdx.x] += rs[threadIdx.x+o]; rss[threadIdx.x] += rss[threadIdx.x+o]; }
        __syncthreads();
    }
    if (threadIdx.x == 0) {
        part[blockIdx.x*2 + 0] = rs[0];
        part[blockIdx.x*2 + 1] = rss[0];
    }
}

__global__ __launch_bounds__(64) void gn_fin(const float* __restrict__ part,
                                             float* __restrict__ stats) {
    int t = threadIdx.x;
    if (t < 32) {
        float s = 0.f, ss = 0.f;
        #pragma unroll
        for (int i = 0; i < 16; ++i) { s += part[(t*16+i)*2]; ss += part[(t*16+i)*2+1]; }
        float inv = 1.0f / (float)(64 * 4096);
        float mu  = s * inv;
        float var = ss * inv - mu * mu;
        stats[t*2 + 0] = mu;
        stats[t*2 + 1] = rsqrtf(var + 1e-5f);
    }
}

// --------------------------------------- GN apply + transpose -> hT [B][4096][512] bf16
__global__ __launch_bounds__(256) void gn_apply_t(const float* __restrict__ x,
                                                  const float* __restrict__ stats,
                                                  const float* __restrict__ gw,
                                                  const float* __restrict__ gb,
                                                  __bf16* __restrict__ hT) {
    __shared__ __bf16 tile[64][88];   // 176B pitch: 16B-aligned rows
    int b = blockIdx.z, c0 = blockIdx.y * 64, n0 = blockIdx.x * 64;
    int t = threadIdx.x;
    float mu  = stats[(b*8 + blockIdx.y)*2];
    float rsg = stats[(b*8 + blockIdx.y)*2 + 1];
    int c = t >> 2, ns = t & 3;
    float a = gw[c0+c] * rsg;
    float d = gb[c0+c] - mu * a;
    const float* xr = x + ((size_t)b*512 + c0 + c)*4096 + n0 + ns*16;
    #pragma unroll
    for (int e4 = 0; e4 < 4; ++e4) {
        float4 v = *(const float4*)(xr + e4*4);
        tile[ns*16 + e4*4 + 0][c] = (__bf16)(v.x*a + d);
        tile[ns*16 + e4*4 + 1][c] = (__bf16)(v.y*a + d);
        tile[ns*16 + e4*4 + 2][c] = (__bf16)(v.z*a + d);
        tile[ns*16 + e4*4 + 3][c] = (__bf16)(v.w*a + d);
    }
    __syncthreads();
    int n = t >> 2, cs = t & 3;
    __bf16* dst = hT + ((size_t)b*4096 + n0 + n)*512 + c0 + cs*16;
    *(uint4*)(dst)     = *(const uint4*)(&tile[n][cs*16]);
    *(uint4*)(dst + 8) = *(const uint4*)(&tile[n][cs*16 + 8]);
}

// ---------------------------------------------------------------- weight f32->bf16
__global__ __launch_bounds__(256) void wconv(const float* __restrict__ src,
                                             __bf16* __restrict__ dst, int n) {
    int i = (blockIdx.x*256 + threadIdx.x) * 4;
    if (i < n) {
        float4 v = *(const float4*)(src + i);
        dst[i+0] = (__bf16)v.x; dst[i+1] = (__bf16)v.y;
        dst[i+2] = (__bf16)v.z; dst[i+3] = (__bf16)v.w;
    }
}

// ---------------------------------------------------------------- 128x128 MFMA GEMM
// 256 thr / 4 waves, wave tile 64x64 = 4x4 accs of 16x16x32, BK=32.
// global_load_lds(16B) linear dest + XOR source-swizzle.
// 3-deep LDS ring + counted vmcnt(4): loads stay in flight across 2 barriers
// (no vmcnt(0) drain in steady state). XCD-chunked bijective block swizzle.
// D[i][j] = sum_k A[i][k]*B[j][k]; A,B bf16 row-major, k contiguous.
// MODE 0: +bias[j], bf16 out                   (QKV -> qkT)
// MODE 1: +bias[i], bf16 out                   (V)
// MODE 2: +bias[i]+res, f32 out                (proj + residual)
// MODE 3: exp(acc*SCALE) -> bf16 P + rowpart   (S-GEMM)
// MODE 4: rsum prologue; acc * 1/rowsum out    (PV-GEMM)
template<int MODE>
__global__ __launch_bounds__(256) void mm128(
        const __bf16* __restrict__ A, int lda, size_t sA,
        const __bf16* __restrict__ B, int ldb, size_t sB,
        int Kdim,
        const float* __restrict__ bias,
        const float* __restrict__ res, size_t sR,
        void* __restrict__ out, int ldo, size_t sO,
        float* __restrict__ rowpart) {
    __shared__ __bf16 As[3][128][32];   // 64B rows, 4 slots of 16B
    __shared__ __bf16 Bs[3][128][32];
    __shared__ float  redp[256];        // MODE 3: [128 rows][2 colwaves]
    __shared__ float  rsum[128];        // MODE 4: 1/rowsum

    const int t = threadIdx.x, w = t >> 6, l = t & 63;
    const int l15 = l & 15, lq = l >> 4;
    const int bz = blockIdx.z;

    // XCD-chunked bijective swizzle of the (x,y) block index (m204)
    const int gx = gridDim.x;
    int lin = blockIdx.y * gx + blockIdx.x;
    {
        const int nwg = gx * gridDim.y;
        const int qn = nwg >> 3, rn = nwg & 7;
        const int xcd = lin & 7, idx = lin >> 3;
        const int base = (xcd < rn) ? xcd*(qn+1) : rn*(qn+1) + (xcd-rn)*qn;
        lin = base + idx;
    }
    const int j0 = (lin % gx) * 128;
    const int i0 = (lin / gx) * 128;

    const __bf16* Ab = A + sA*bz;
    const __bf16* Bb = B + sB*bz;
    const int rowblk = (w & 1)*64;      // wave's row sub-block
    const int colblk = (w >> 1)*64;     // wave's col sub-block

    if constexpr (MODE == 4) {
        if (t < 128) {
            const float* rp = rowpart + (size_t)bz*131072 + i0 + t;
            float s = 0.f;
            #pragma unroll
            for (int jb = 0; jb < 32; ++jb) s += rp[jb*4096];
            rsum[t] = 1.0f / s;   // consumed in epilogue; loop barriers order it
        }
    }

    // staging: 512 slots/array (row = slot>>2, 16B-slot = slot&3), 2 issues of 256.
    // LDS dest linear; global source pre-swizzled (involution slot^((row>>1)&3)).
    const int slot0 = w*64 + l;
    const int rowS0 = slot0 >> 2;
    const int rowS1 = rowS0 + 64;
    const int csS   = (((slot0 & 3) ^ ((rowS0 >> 1) & 3))) * 8;
    const int off0  = (w*64)*16;
    const int off1  = (256 + w*64)*16;

    f32x4 acc[4][4];
    #pragma unroll
    for (int mr = 0; mr < 4; ++mr)
        #pragma unroll
        for (int nr = 0; nr < 4; ++nr)
            #pragma unroll
            for (int r = 0; r < 4; ++r) acc[mr][nr][r] = 0.f;

    auto STAGE = [&](int kc, int bi) {   // exactly 4 vmem ops
        char* Ad = (char*)As[bi];
        char* Bd = (char*)Bs[bi];
        gload16(Ab + (size_t)(i0 + rowS0)*lda + kc + csS, Ad + off0);
        gload16(Ab + (size_t)(i0 + rowS1)*lda + kc + csS, Ad + off1);
        gload16(Bb + (size_t)(j0 + rowS0)*ldb + kc + csS, Bd + off0);
        gload16(Bb + (size_t)(j0 + rowS1)*ldb + kc + csS, Bd + off1);
    };

    const int rsw = (l15 >> 1) & 3;      // (row>>1)&3 contribution from l15
    const int koff = (lq ^ rsw) << 4;    // swizzled 16B slot offset for frag reads

    const int nch = Kdim >> 5;           // BK=32
    STAGE(0, 0);
    STAGE(32, 1);

    for (int cc = 0; cc < nch; ++cc) {
        // buf[cc%3] ready once this wave's STAGE(cc) retired; 4 newer loads may fly.
        if (cc < nch - 1) asm volatile("s_waitcnt vmcnt(4)\n\ts_barrier" ::: "memory");
        else              asm volatile("s_waitcnt vmcnt(0)\n\ts_barrier" ::: "memory");

        const char* Ac = (const char*)As[cc % 3];
        const char* Bc = (const char*)Bs[cc % 3];
        bf16x8 av[4], bv[4];
        #pragma unroll
        for (int mr = 0; mr < 4; ++mr) {
            int row = rowblk + mr*16 + l15;
            av[mr] = *(const bf16x8*)(Ac + row*64 + koff);
        }
        #pragma unroll
        for (int nr = 0; nr < 4; ++nr) {
            int row = colblk + nr*16 + l15;
            bv[nr] = *(const bf16x8*)(Bc + row*64 + koff);
        }
        if (cc + 2 < nch) STAGE((cc + 2)*32, (cc + 2) % 3);
        #pragma unroll
        for (int mr = 0; mr < 4; ++mr)
            #pragma unroll
            for (int nr = 0; nr < 4; ++nr)
                acc[mr][nr] = __builtin_amdgcn_mfma_f32_16x16x32_bf16(av[mr], bv[nr], acc[mr][nr], 0, 0, 0);
    }

    const int jblk = j0 >> 7;   // swizzled j-block index (for rowpart)

    if constexpr (MODE == 3) {
        float rpart[4][4];
        #pragma unroll
        for (int mr = 0; mr < 4; ++mr)
            #pragma unroll
            for (int r = 0; r < 4; ++r) rpart[mr][r] = 0.f;
        #pragma unroll
        for (int mr = 0; mr < 4; ++mr)
            #pragma unroll
            for (int nr = 0; nr < 4; ++nr) {
                int col = j0 + colblk + nr*16 + l15;
                #pragma unroll
                for (int r = 0; r < 4; ++r) {
                    int row = rowblk + mr*16 + lq*4 + r;
                    float e = __expf(acc[mr][nr][r] * SCALE);
                    ((__bf16*)out)[sO*bz + (size_t)(i0 + row)*ldo + col] = (__bf16)e;
                    rpart[mr][r] += e;
                }
            }
        #pragma unroll
        for (int m = 1; m < 16; m <<= 1)
            #pragma unroll
            for (int mr = 0; mr < 4; ++mr)
                #pragma unroll
                for (int r = 0; r < 4; ++r)
                    rpart[mr][r] += __shfl_xor(rpart[mr][r], m);
        if (l15 == 0) {
            #pragma unroll
            for (int mr = 0; mr < 4; ++mr)
                #pragma unroll
                for (int r = 0; r < 4; ++r)
                    redp[(rowblk + mr*16 + lq*4 + r)*2 + (w >> 1)] = rpart[mr][r];
        }
        __syncthreads();
        if (t < 128)
            rowpart[(size_t)bz*131072 + (size_t)jblk*4096 + i0 + t] =
                redp[t*2] + redp[t*2 + 1];
        return;
    }

    #pragma unroll
    for (int mr = 0; mr < 4; ++mr)
        #pragma unroll
        for (int nr = 0; nr < 4; ++nr) {
            int col = j0 + colblk + nr*16 + l15;
            #pragma unroll
            for (int r = 0; r < 4; ++r) {
                int lrow = rowblk + mr*16 + lq*4 + r;
                int gi = i0 + lrow;
                float v = acc[mr][nr][r];
                if constexpr (MODE == 0) {
                    v += bias[col];
                    ((__bf16*)out)[sO*bz + (size_t)gi*ldo + col] = (__bf16)v;
                } else if constexpr (MODE == 1) {
                    v += bias[gi];
                    ((__bf16*)out)[sO*bz + (size_t)gi*ldo + col] = (__bf16)v;
                } else if constexpr (MODE == 2) {
                    v += bias[gi] + res[sR*bz + (size_t)gi*ldo + col];
                    ((float*)out)[sO*bz + (size_t)gi*ldo + col] = v;
                } else {  // MODE 4
                    v *= rsum[lrow];
                    ((__bf16*)out)[sO*bz + (size_t)gi*ldo + col] = (__bf16)v;
                }
            }
        }
}

extern "C" void kernel_launch(void* const* d_in, const int* in_sizes, int n_in,
                              void* d_out, int out_size, void* d_ws, size_t ws_size,
                              hipStream_t stream) {
    const float* x      = (const float*)d_in[0];
    const float* gn_w   = (const float*)d_in[1];
    const float* gn_b   = (const float*)d_in[2];
    const float* qkv_w  = (const float*)d_in[3];
    const float* qkv_b  = (const float*)d_in[4];
    const float* proj_w = (const float*)d_in[5];
    const float* proj_b = (const float*)d_in[6];

    char* w8 = (char*)d_ws;
    __bf16* qkT  = (__bf16*)(w8);                 // 32 MB  [B][4096][1024]
    __bf16* Vbuf = (__bf16*)(w8 + 33554432);      // 16 MB  [B][512][4096]
    __bf16* OT   = (__bf16*)(w8 + 50331648);      // 16 MB  [B][4096][512]
    __bf16* wq   = (__bf16*)(w8 + 67108864);      // 1.5 MB [1536][512]
    __bf16* pw   = (__bf16*)(w8 + 68681728);      // 0.5 MB [512][512]
    float*  rowpart = (float*)(w8 + 69206016);    // 2 MB   [4][32][4096]
    float*  part = (float*)(w8 + 71303168);       // 4 KB gn partials
    float*  st   = (float*)(w8 + 71307264);       // 256 B stats
    const size_t baseP = 71307520ULL;
    __bf16* hT   = (__bf16*)(w8 + baseP);         // 16 MB [B][4096][512] (dead after QKV)
    __bf16* P    = (__bf16*)(w8 + baseP);         // P chunks alias hT

    size_t avail = (ws_size > baseP) ? (ws_size - baseP) : 0;
    int cap = (int)(avail / 33554432ULL);
    if (cap < 1) cap = 1;
    if (cap > 4) cap = 4;

    wconv<<<768, 256, 0, stream>>>(qkv_w, wq, 1536*512);
    wconv<<<256, 256, 0, stream>>>(proj_w, pw, 512*512);
    gn_part<<<512, 256, 0, stream>>>(x, part);
    gn_fin<<<1, 64, 0, stream>>>(part, st);
    gn_apply_t<<<dim3(64, 8, 4), 256, 0, stream>>>(x, st, gn_w, gn_b, hT);

    // qkT[b][n][o] = sum_c hT[b][n][c]*qkv_w[o][c] + qkv_b[o], o in [0,1024)
    mm128<0><<<dim3(8, 32, 4), 256, 0, stream>>>(
        hT, 512, (size_t)4096*512, wq, 512, 0, 512,
        qkv_b, nullptr, 0, qkT, 1024, (size_t)4096*1024, nullptr);
    // V[b][o][n] = sum_c qkv_w[1024+o][c]*hT[b][n][c] + qkv_b[1024+o]
    mm128<1><<<dim3(32, 4, 4), 256, 0, stream>>>(
        wq + (size_t)1024*512, 512, 0, hT, 512, (size_t)4096*512, 512,
        qkv_b + 1024, nullptr, 0, Vbuf, 4096, (size_t)512*4096, nullptr);

    for (int b0 = 0; b0 < 4; b0 += cap) {
        int c = (4 - b0 < cap) ? (4 - b0) : cap;
        // P[z][q][key] = exp(SCALE * sum_c Q[q][c]K[key][c]); rowpart written
        mm128<3><<<dim3(32, 32, c), 256, 0, stream>>>(
            qkT + (size_t)b0*4194304, 1024, (size_t)4096*1024,
            qkT + (size_t)b0*4194304 + 512, 1024, (size_t)4096*1024, 512,
            nullptr, nullptr, 0, P, 4096, (size_t)4096*4096,
            rowpart + (size_t)b0*131072);
        // OT[z][q][c] = (sum_key P[q][key]V[c][key]) / rowsum[q]
        mm128<4><<<dim3(4, 32, c), 256, 0, stream>>>(
            P, 4096, (size_t)4096*4096,
            Vbuf + (size_t)b0*2097152, 4096, (size_t)512*4096, 4096,
            nullptr, nullptr, 0, OT + (size_t)b0*2097152, 512, (size_t)4096*512,
            rowpart + (size_t)b0*131072);
    }

    // out[b][co][n] = x + sum_c proj_w[co][c]*OT[b][n][c] + proj_b[co]
    mm128<2><<<dim3(32, 4, 4), 256, 0, stream>>>(
        pw, 512, 0, OT, 512, (size_t)4096*512, 512,
        proj_b, x, (size_t)512*4096, (float*)d_out, 4096, (size_t)512*4096, nullptr);
}

// Round 9
// 273.430 us; speedup vs baseline: 23.8114x; 1.0137x over previous
//
#include <hip/hip_runtime.h>
#include <math.h>

#define SCALE 0.044194173824159216f  // 512^-0.5

typedef __bf16 bf16x8 __attribute__((ext_vector_type(8)));
typedef float  f32x4  __attribute__((ext_vector_type(4)));
typedef unsigned int u32;

__device__ __forceinline__ void gload16(const void* g, void* l) {
    __builtin_amdgcn_global_load_lds(
        (const __attribute__((address_space(1))) u32*)g,
        (__attribute__((address_space(3))) u32*)l, 16, 0, 0);
}

// ---------------------------------------------------------------- GroupNorm stats (2-stage)
__global__ __launch_bounds__(256) void gn_part(const float* __restrict__ x,
                                               float* __restrict__ part) {
    int gi = blockIdx.x >> 4, sl = blockIdx.x & 15;   // gi = b*8+g
    const float4* p = (const float4*)(x + (size_t)gi * 64 * 4096) + (size_t)sl * 4096;
    float s = 0.f, ss = 0.f;
    #pragma unroll 4
    for (int i = threadIdx.x; i < 4096; i += 256) {
        float4 v = p[i];
        s  += v.x + v.y + v.z + v.w;
        ss += v.x*v.x + v.y*v.y + v.z*v.z + v.w*v.w;
    }
    __shared__ float rs[256], rss[256];
    rs[threadIdx.x] = s; rss[threadIdx.x] = ss;
    __syncthreads();
    for (int o = 128; o > 0; o >>= 1) {
        if (threadIdx.x < o) { rs[threadIdx.x] += rs[threadIdx.x+o]; rss[threadIdx.x] += rss[threadIdx.x+o]; }
        __syncthreads();
    }
    if (threadIdx.x == 0) {
        part[blockIdx.x*2 + 0] = rs[0];
        part[blockIdx.x*2 + 1] = rss[0];
    }
}

__global__ __launch_bounds__(64) void gn_fin(const float* __restrict__ part,
                                             float* __restrict__ stats) {
    int t = threadIdx.x;
    if (t < 32) {
        float s = 0.f, ss = 0.f;
        #pragma unroll
        for (int i = 0; i < 16; ++i) { s += part[(t*16+i)*2]; ss += part[(t*16+i)*2+1]; }
        float inv = 1.0f / (float)(64 * 4096);
        float mu  = s * inv;
        float var = ss * inv - mu * mu;
        stats[t*2 + 0] = mu;
        stats[t*2 + 1] = rsqrtf(var + 1e-5f);
    }
}

// --------------------------------------- GN apply + transpose -> hT [B][4096][512] bf16
__global__ __launch_bounds__(256) void gn_apply_t(const float* __restrict__ x,
                                                  const float* __restrict__ stats,
                                                  const float* __restrict__ gw,
                                                  const float* __restrict__ gb,
                                                  __bf16* __restrict__ hT) {
    __shared__ __bf16 tile[64][88];   // 176B pitch: 16B-aligned rows
    int b = blockIdx.z, c0 = blockIdx.y * 64, n0 = blockIdx.x * 64;
    int t = threadIdx.x;
    float mu  = stats[(b*8 + blockIdx.y)*2];
    float rsg = stats[(b*8 + blockIdx.y)*2 + 1];
    int c = t >> 2, ns = t & 3;
    float a = gw[c0+c] * rsg;
    float d = gb[c0+c] - mu * a;
    const float* xr = x + ((size_t)b*512 + c0 + c)*4096 + n0 + ns*16;
    #pragma unroll
    for (int e4 = 0; e4 < 4; ++e4) {
        float4 v = *(const float4*)(xr + e4*4);
        tile[ns*16 + e4*4 + 0][c] = (__bf16)(v.x*a + d);
        tile[ns*16 + e4*4 + 1][c] = (__bf16)(v.y*a + d);
        tile[ns*16 + e4*4 + 2][c] = (__bf16)(v.z*a + d);
        tile[ns*16 + e4*4 + 3][c] = (__bf16)(v.w*a + d);
    }
    __syncthreads();
    int n = t >> 2, cs = t & 3;
    __bf16* dst = hT + ((size_t)b*4096 + n0 + n)*512 + c0 + cs*16;
    *(uint4*)(dst)     = *(const uint4*)(&tile[n][cs*16]);
    *(uint4*)(dst + 8) = *(const uint4*)(&tile[n][cs*16 + 8]);
}

// ---------------------------------------------------------------- weight f32->bf16
__global__ __launch_bounds__(256) void wconv(const float* __restrict__ src,
                                             __bf16* __restrict__ dst, int n) {
    int i = (blockIdx.x*256 + threadIdx.x) * 4;
    if (i < n) {
        float4 v = *(const float4*)(src + i);
        dst[i+0] = (__bf16)v.x; dst[i+1] = (__bf16)v.y;
        dst[i+2] = (__bf16)v.z; dst[i+3] = (__bf16)v.w;
    }
}

// ---------------------------------------------------------------- 128x128 MFMA GEMM
// (kept for MODE 0/1/2 small GEMMs) 256 thr / 4 waves, wave tile 64x64, BK=32,
// 3-ring, counted vmcnt(4), gload16 linear dest + XOR source swizzle.
template<int MODE>
__global__ __launch_bounds__(256) void mm128(
        const __bf16* __restrict__ A, int lda, size_t sA,
        const __bf16* __restrict__ B, int ldb, size_t sB,
        int Kdim,
        const float* __restrict__ bias,
        const float* __restrict__ res, size_t sR,
        void* __restrict__ out, int ldo, size_t sO) {
    __shared__ __bf16 As[3][128][32];
    __shared__ __bf16 Bs[3][128][32];

    const int t = threadIdx.x, w = t >> 6, l = t & 63;
    const int l15 = l & 15, lq = l >> 4;
    const int bz = blockIdx.z;

    const int gx = gridDim.x;
    int lin = blockIdx.y * gx + blockIdx.x;
    {
        const int nwg = gx * gridDim.y;
        const int qn = nwg >> 3, rn = nwg & 7;
        const int xcd = lin & 7, idx = lin >> 3;
        const int base = (xcd < rn) ? xcd*(qn+1) : rn*(qn+1) + (xcd-rn)*qn;
        lin = base + idx;
    }
    const int j0 = (lin % gx) * 128;
    const int i0 = (lin / gx) * 128;

    const __bf16* Ab = A + sA*bz;
    const __bf16* Bb = B + sB*bz;
    const int rowblk = (w & 1)*64;
    const int colblk = (w >> 1)*64;

    const int slot0 = w*64 + l;
    const int rowS0 = slot0 >> 2;
    const int rowS1 = rowS0 + 64;
    const int csS   = (((slot0 & 3) ^ ((rowS0 >> 1) & 3))) * 8;
    const int off0  = (w*64)*16;
    const int off1  = (256 + w*64)*16;

    f32x4 acc[4][4];
    #pragma unroll
    for (int mr = 0; mr < 4; ++mr)
        #pragma unroll
        for (int nr = 0; nr < 4; ++nr)
            #pragma unroll
            for (int r = 0; r < 4; ++r) acc[mr][nr][r] = 0.f;

    auto STAGE = [&](int kc, int bi) {
        char* Ad = (char*)As[bi];
        char* Bd = (char*)Bs[bi];
        gload16(Ab + (size_t)(i0 + rowS0)*lda + kc + csS, Ad + off0);
        gload16(Ab + (size_t)(i0 + rowS1)*lda + kc + csS, Ad + off1);
        gload16(Bb + (size_t)(j0 + rowS0)*ldb + kc + csS, Bd + off0);
        gload16(Bb + (size_t)(j0 + rowS1)*ldb + kc + csS, Bd + off1);
    };

    const int rsw = (l15 >> 1) & 3;
    const int koff = (lq ^ rsw) << 4;

    const int nch = Kdim >> 5;
    STAGE(0, 0);
    STAGE(32, 1);

    for (int cc = 0; cc < nch; ++cc) {
        if (cc < nch - 1) asm volatile("s_waitcnt vmcnt(4)\n\ts_barrier" ::: "memory");
        else              asm volatile("s_waitcnt vmcnt(0)\n\ts_barrier" ::: "memory");

        const char* Ac = (const char*)As[cc % 3];
        const char* Bc = (const char*)Bs[cc % 3];
        bf16x8 av[4], bv[4];
        #pragma unroll
        for (int mr = 0; mr < 4; ++mr)
            av[mr] = *(const bf16x8*)(Ac + (rowblk + mr*16 + l15)*64 + koff);
        #pragma unroll
        for (int nr = 0; nr < 4; ++nr)
            bv[nr] = *(const bf16x8*)(Bc + (colblk + nr*16 + l15)*64 + koff);
        if (cc + 2 < nch) STAGE((cc + 2)*32, (cc + 2) % 3);
        #pragma unroll
        for (int mr = 0; mr < 4; ++mr)
            #pragma unroll
            for (int nr = 0; nr < 4; ++nr)
                acc[mr][nr] = __builtin_amdgcn_mfma_f32_16x16x32_bf16(av[mr], bv[nr], acc[mr][nr], 0, 0, 0);
    }

    #pragma unroll
    for (int mr = 0; mr < 4; ++mr)
        #pragma unroll
        for (int nr = 0; nr < 4; ++nr) {
            int col = j0 + colblk + nr*16 + l15;
            #pragma unroll
            for (int r = 0; r < 4; ++r) {
                int lrow = rowblk + mr*16 + lq*4 + r;
                int gi = i0 + lrow;
                float v = acc[mr][nr][r];
                if constexpr (MODE == 0) {
                    v += bias[col];
                    ((__bf16*)out)[sO*bz + (size_t)gi*ldo + col] = (__bf16)v;
                } else if constexpr (MODE == 1) {
                    v += bias[gi];
                    ((__bf16*)out)[sO*bz + (size_t)gi*ldo + col] = (__bf16)v;
                } else {
                    v += bias[gi] + res[sR*bz + (size_t)gi*ldo + col];
                    ((float*)out)[sO*bz + (size_t)gi*ldo + col] = v;
                }
            }
        }
}

// ---------------------------------------------------------------- 256x256 MFMA GEMM
// 512 thr / 8 waves (2M x 4N), wave tile 128x64 = 8x4 accs of 16x16x32, BK=32.
// Per chunk: 12 ds_read_b128 -> 32 MFMA (2x the MFMA per barrier of mm128).
// Same proven schedule: 3-ring LDS (dynamic, 96KB), vmcnt(4)+barrier,
// gload16 linear dest + XOR source swizzle. XCD-chunked block swizzle.
// MODE 3: exp(acc*SCALE) -> bf16 P + rowpart   (S-GEMM)
// MODE 4: rsum prologue; acc * 1/rowsum out    (PV-GEMM)
#define LDSB (98304 + 4096)
template<int MODE>
__global__ __launch_bounds__(512) void mm256(
        const __bf16* __restrict__ A, int lda, size_t sA,
        const __bf16* __restrict__ B, int ldb, size_t sB,
        int Kdim,
        void* __restrict__ out, int ldo, size_t sO,
        float* __restrict__ rowpart) {
    extern __shared__ char smem[];
    char*  Abase = smem;             // 3 x 16KB  [256 rows][32 k] each
    char*  Bbase = smem + 49152;     // 3 x 16KB
    float* redp  = (float*)(smem + 98304);   // MODE3: [256][4]
    float* rsum  = (float*)(smem + 98304);   // MODE4: [256]

    const int t = threadIdx.x, w = t >> 6, l = t & 63;
    const int l15 = l & 15, lq = l >> 4;
    const int bz = blockIdx.z;

    const int gx = gridDim.x;
    int lin = blockIdx.y * gx + blockIdx.x;
    {
        const int nwg = gx * gridDim.y;
        const int qn = nwg >> 3, rn = nwg & 7;
        const int xcd = lin & 7, idx = lin >> 3;
        const int base = (xcd < rn) ? xcd*(qn+1) : rn*(qn+1) + (xcd-rn)*qn;
        lin = base + idx;
    }
    const int j0 = (lin % gx) * 256;
    const int i0 = (lin / gx) * 256;

    const __bf16* Ab = A + sA*bz;
    const __bf16* Bb = B + sB*bz;
    const int wr = w & 1;            // M half (128 rows)
    const int wc = w >> 1;           // N quarter (64 cols)

    if constexpr (MODE == 4) {
        if (t < 256) {
            const float* rp = rowpart + (size_t)bz*131072 + i0 + t;
            float s = 0.f;
            #pragma unroll
            for (int jb = 0; jb < 16; ++jb) s += rp[jb*4096];
            rsum[t] = 1.0f / s;
        }
    }

    // staging: 1024 slots/array (row = slot>>2 in [0,256), kslot = slot&3).
    // thread t: slots t and t+512. source XOR-swizzle kslot ^= (row>>1)&3.
    const int slot0 = w*64 + l;
    const int rowS0 = slot0 >> 2;
    const int rowS1 = rowS0 + 128;   // slot0+512
    const int csS   = (((slot0 & 3) ^ ((rowS0 >> 1) & 3))) * 8;
    const int off0  = (w*64)*16;
    const int off1  = (512 + w*64)*16;

    f32x4 acc[8][4];
    #pragma unroll
    for (int mr = 0; mr < 8; ++mr)
        #pragma unroll
        for (int nr = 0; nr < 4; ++nr)
            #pragma unroll
            for (int r = 0; r < 4; ++r) acc[mr][nr][r] = 0.f;

    auto STAGE = [&](int kc, int bi) {   // 4 vmem ops per thread
        char* Ad = Abase + bi*16384;
        char* Bd = Bbase + bi*16384;
        gload16(Ab + (size_t)(i0 + rowS0)*lda + kc + csS, Ad + off0);
        gload16(Ab + (size_t)(i0 + rowS1)*lda + kc + csS, Ad + off1);
        gload16(Bb + (size_t)(j0 + rowS0)*ldb + kc + csS, Bd + off0);
        gload16(Bb + (size_t)(j0 + rowS1)*ldb + kc + csS, Bd + off1);
    };

    const int rsw = (l15 >> 1) & 3;
    const int koff = (lq ^ rsw) << 4;

    const int nch = Kdim >> 5;
    STAGE(0, 0);
    STAGE(32, 1);

    for (int cc = 0; cc < nch; ++cc) {
        if (cc < nch - 1) asm volatile("s_waitcnt vmcnt(4)\n\ts_barrier" ::: "memory");
        else              asm volatile("s_waitcnt vmcnt(0)\n\ts_barrier" ::: "memory");

        const char* Ac = Abase + (cc % 3)*16384;
        const char* Bc = Bbase + (cc % 3)*16384;
        bf16x8 av[8], bv[4];
        #pragma unroll
        for (int mr = 0; mr < 8; ++mr)
            av[mr] = *(const bf16x8*)(Ac + (wr*128 + mr*16 + l15)*64 + koff);
        #pragma unroll
        for (int nr = 0; nr < 4; ++nr)
            bv[nr] = *(const bf16x8*)(Bc + (wc*64 + nr*16 + l15)*64 + koff);
        if (cc + 2 < nch) STAGE((cc + 2)*32, (cc + 2) % 3);
        #pragma unroll
        for (int mr = 0; mr < 8; ++mr)
            #pragma unroll
            for (int nr = 0; nr < 4; ++nr)
                acc[mr][nr] = __builtin_amdgcn_mfma_f32_16x16x32_bf16(av[mr], bv[nr], acc[mr][nr], 0, 0, 0);
    }

    if constexpr (MODE == 3) {
        const int jblk = j0 >> 8;
        float rpart[8][4];
        #pragma unroll
        for (int mr = 0; mr < 8; ++mr)
            #pragma unroll
            for (int r = 0; r < 4; ++r) rpart[mr][r] = 0.f;
        #pragma unroll
        for (int mr = 0; mr < 8; ++mr)
            #pragma unroll
            for (int nr = 0; nr < 4; ++nr) {
                int col = j0 + wc*64 + nr*16 + l15;
                #pragma unroll
                for (int r = 0; r < 4; ++r) {
                    int row = wr*128 + mr*16 + lq*4 + r;
                    float e = __expf(acc[mr][nr][r] * SCALE);
                    ((__bf16*)out)[sO*bz + (size_t)(i0 + row)*ldo + col] = (__bf16)e;
                    rpart[mr][r] += e;
                }
            }
        #pragma unroll
        for (int m = 1; m < 16; m <<= 1)
            #pragma unroll
            for (int mr = 0; mr < 8; ++mr)
                #pragma unroll
                for (int r = 0; r < 4; ++r)
                    rpart[mr][r] += __shfl_xor(rpart[mr][r], m);
        if (l15 == 0) {
            #pragma unroll
            for (int mr = 0; mr < 8; ++mr)
                #pragma unroll
                for (int r = 0; r < 4; ++r)
                    redp[(wr*128 + mr*16 + lq*4 + r)*4 + wc] = rpart[mr][r];
        }
        __syncthreads();
        if (t < 256)
            rowpart[(size_t)bz*131072 + (size_t)jblk*4096 + i0 + t] =
                redp[t*4+0] + redp[t*4+1] + redp[t*4+2] + redp[t*4+3];
        return;
    }

    // MODE 4
    #pragma unroll
    for (int mr = 0; mr < 8; ++mr)
        #pragma unroll
        for (int nr = 0; nr < 4; ++nr) {
            int col = j0 + wc*64 + nr*16 + l15;
            #pragma unroll
            for (int r = 0; r < 4; ++r) {
                int lrow = wr*128 + mr*16 + lq*4 + r;
                float v = acc[mr][nr][r] * rsum[lrow];
                ((__bf16*)out)[sO*bz + (size_t)(i0 + lrow)*ldo + col] = (__bf16)v;
            }
        }
}

extern "C" void kernel_launch(void* const* d_in, const int* in_sizes, int n_in,
                              void* d_out, int out_size, void* d_ws, size_t ws_size,
                              hipStream_t stream) {
    const float* x      = (const float*)d_in[0];
    const float* gn_w   = (const float*)d_in[1];
    const float* gn_b   = (const float*)d_in[2];
    const float* qkv_w  = (const float*)d_in[3];
    const float* qkv_b  = (const float*)d_in[4];
    const float* proj_w = (const float*)d_in[5];
    const float* proj_b = (const float*)d_in[6];

    char* w8 = (char*)d_ws;
    __bf16* qkT  = (__bf16*)(w8);                 // 32 MB  [B][4096][1024]
    __bf16* Vbuf = (__bf16*)(w8 + 33554432);      // 16 MB  [B][512][4096]
    __bf16* OT   = (__bf16*)(w8 + 50331648);      // 16 MB  [B][4096][512]
    __bf16* wq   = (__bf16*)(w8 + 67108864);      // 1.5 MB [1536][512]
    __bf16* pw   = (__bf16*)(w8 + 68681728);      // 0.5 MB [512][512]
    float*  rowpart = (float*)(w8 + 69206016);    // 2 MB   [4][16][4096] (stride 131072)
    float*  part = (float*)(w8 + 71303168);       // 4 KB gn partials
    float*  st   = (float*)(w8 + 71307264);       // 256 B stats
    const size_t baseP = 71307520ULL;
    __bf16* hT   = (__bf16*)(w8 + baseP);         // 16 MB [B][4096][512] (dead after QKV)
    __bf16* P    = (__bf16*)(w8 + baseP);         // P chunks alias hT

    size_t avail = (ws_size > baseP) ? (ws_size - baseP) : 0;
    int cap = (int)(avail / 33554432ULL);
    if (cap < 1) cap = 1;
    if (cap > 4) cap = 4;

    hipFuncSetAttribute((const void*)mm256<3>,
                        hipFuncAttributeMaxDynamicSharedMemorySize, LDSB);
    hipFuncSetAttribute((const void*)mm256<4>,
                        hipFuncAttributeMaxDynamicSharedMemorySize, LDSB);

    wconv<<<768, 256, 0, stream>>>(qkv_w, wq, 1536*512);
    wconv<<<256, 256, 0, stream>>>(proj_w, pw, 512*512);
    gn_part<<<512, 256, 0, stream>>>(x, part);
    gn_fin<<<1, 64, 0, stream>>>(part, st);
    gn_apply_t<<<dim3(64, 8, 4), 256, 0, stream>>>(x, st, gn_w, gn_b, hT);

    // qkT[b][n][o] = sum_c hT[b][n][c]*qkv_w[o][c] + qkv_b[o], o in [0,1024)
    mm128<0><<<dim3(8, 32, 4), 256, 0, stream>>>(
        hT, 512, (size_t)4096*512, wq, 512, 0, 512,
        qkv_b, nullptr, 0, qkT, 1024, (size_t)4096*1024);
    // V[b][o][n] = sum_c qkv_w[1024+o][c]*hT[b][n][c] + qkv_b[1024+o]
    mm128<1><<<dim3(32, 4, 4), 256, 0, stream>>>(
        wq + (size_t)1024*512, 512, 0, hT, 512, (size_t)4096*512, 512,
        qkv_b + 1024, nullptr, 0, Vbuf, 4096, (size_t)512*4096);

    for (int b0 = 0; b0 < 4; b0 += cap) {
        int c = (4 - b0 < cap) ? (4 - b0) : cap;
        // P[z][q][key] = exp(SCALE * sum_c Q[q][c]K[key][c]); rowpart written
        mm256<3><<<dim3(16, 16, c), 512, LDSB, stream>>>(
            qkT + (size_t)b0*4194304, 1024, (size_t)4096*1024,
            qkT + (size_t)b0*4194304 + 512, 1024, (size_t)4096*1024, 512,
            P, 4096, (size_t)4096*4096,
            rowpart + (size_t)b0*131072);
        // OT[z][q][c] = (sum_key P[q][key]V[c][key]) / rowsum[q]
        mm256<4><<<dim3(2, 16, c), 512, LDSB, stream>>>(
            P, 4096, (size_t)4096*4096,
            Vbuf + (size_t)b0*2097152, 4096, (size_t)512*4096, 4096,
            OT + (size_t)b0*2097152, 512, (size_t)4096*512,
            rowpart + (size_t)b0*131072);
    }

    // out[b][co][n] = x + sum_c proj_w[co][c]*OT[b][n][c] + proj_b[co]
    mm128<2><<<dim3(32, 4, 4), 256, 0, stream>>>(
        pw, 512, 0, OT, 512, (size_t)4096*512, 512,
        proj_b, x, (size_t)512*4096, (float*)d_out, 4096, (size_t)512*4096);
}

// Round 10
// 251.168 us; speedup vs baseline: 25.9219x; 1.0886x over previous
//
#include <hip/hip_runtime.h>
#include <math.h>

#define SCALE 0.044194173824159216f  // 512^-0.5

typedef __bf16 bf16x8 __attribute__((ext_vector_type(8)));
typedef float  f32x4  __attribute__((ext_vector_type(4)));
typedef unsigned int u32;

__device__ __forceinline__ void gload16(const void* g, void* l) {
    __builtin_amdgcn_global_load_lds(
        (const __attribute__((address_space(1))) u32*)g,
        (__attribute__((address_space(3))) u32*)l, 16, 0, 0);
}

// ---------------------------------------------------------------- GroupNorm stats (2-stage)
__global__ __launch_bounds__(256) void gn_part(const float* __restrict__ x,
                                               float* __restrict__ part) {
    int gi = blockIdx.x >> 4, sl = blockIdx.x & 15;   // gi = b*8+g
    const float4* p = (const float4*)(x + (size_t)gi * 64 * 4096) + (size_t)sl * 4096;
    float s = 0.f, ss = 0.f;
    #pragma unroll 4
    for (int i = threadIdx.x; i < 4096; i += 256) {
        float4 v = p[i];
        s  += v.x + v.y + v.z + v.w;
        ss += v.x*v.x + v.y*v.y + v.z*v.z + v.w*v.w;
    }
    __shared__ float rs[256], rss[256];
    rs[threadIdx.x] = s; rss[threadIdx.x] = ss;
    __syncthreads();
    for (int o = 128; o > 0; o >>= 1) {
        if (threadIdx.x < o) { rs[threadIdx.x] += rs[threadIdx.x+o]; rss[threadIdx.x] += rss[threadIdx.x+o]; }
        __syncthreads();
    }
    if (threadIdx.x == 0) {
        part[blockIdx.x*2 + 0] = rs[0];
        part[blockIdx.x*2 + 1] = rss[0];
    }
}

__global__ __launch_bounds__(64) void gn_fin(const float* __restrict__ part,
                                             float* __restrict__ stats) {
    int t = threadIdx.x;
    if (t < 32) {
        float s = 0.f, ss = 0.f;
        #pragma unroll
        for (int i = 0; i < 16; ++i) { s += part[(t*16+i)*2]; ss += part[(t*16+i)*2+1]; }
        float inv = 1.0f / (float)(64 * 4096);
        float mu  = s * inv;
        float var = ss * inv - mu * mu;
        stats[t*2 + 0] = mu;
        stats[t*2 + 1] = rsqrtf(var + 1e-5f);
    }
}

// --------------------------------------- GN apply + transpose -> hT [B][4096][512] bf16
__global__ __launch_bounds__(256) void gn_apply_t(const float* __restrict__ x,
                                                  const float* __restrict__ stats,
                                                  const float* __restrict__ gw,
                                                  const float* __restrict__ gb,
                                                  __bf16* __restrict__ hT) {
    __shared__ __bf16 tile[64][88];   // 176B pitch: 16B-aligned rows
    int b = blockIdx.z, c0 = blockIdx.y * 64, n0 = blockIdx.x * 64;
    int t = threadIdx.x;
    float mu  = stats[(b*8 + blockIdx.y)*2];
    float rsg = stats[(b*8 + blockIdx.y)*2 + 1];
    int c = t >> 2, ns = t & 3;
    float a = gw[c0+c] * rsg;
    float d = gb[c0+c] - mu * a;
    const float* xr = x + ((size_t)b*512 + c0 + c)*4096 + n0 + ns*16;
    #pragma unroll
    for (int e4 = 0; e4 < 4; ++e4) {
        float4 v = *(const float4*)(xr + e4*4);
        tile[ns*16 + e4*4 + 0][c] = (__bf16)(v.x*a + d);
        tile[ns*16 + e4*4 + 1][c] = (__bf16)(v.y*a + d);
        tile[ns*16 + e4*4 + 2][c] = (__bf16)(v.z*a + d);
        tile[ns*16 + e4*4 + 3][c] = (__bf16)(v.w*a + d);
    }
    __syncthreads();
    int n = t >> 2, cs = t & 3;
    __bf16* dst = hT + ((size_t)b*4096 + n0 + n)*512 + c0 + cs*16;
    *(uint4*)(dst)     = *(const uint4*)(&tile[n][cs*16]);
    *(uint4*)(dst + 8) = *(const uint4*)(&tile[n][cs*16 + 8]);
}

// ---------------------------------------------------------------- weight f32->bf16
__global__ __launch_bounds__(256) void wconv(const float* __restrict__ src,
                                             __bf16* __restrict__ dst, int n) {
    int i = (blockIdx.x*256 + threadIdx.x) * 4;
    if (i < n) {
        float4 v = *(const float4*)(src + i);
        dst[i+0] = (__bf16)v.x; dst[i+1] = (__bf16)v.y;
        dst[i+2] = (__bf16)v.z; dst[i+3] = (__bf16)v.w;
    }
}

// ---------------------------------------------------------------- 128x128 MFMA GEMM
// (kept for MODE 1/2 small GEMMs) 256 thr / 4 waves, wave tile 64x64, BK=32,
// 3-ring, counted vmcnt(4), gload16 linear dest + XOR source swizzle.
template<int MODE>
__global__ __launch_bounds__(256) void mm128(
        const __bf16* __restrict__ A, int lda, size_t sA,
        const __bf16* __restrict__ B, int ldb, size_t sB,
        int Kdim,
        const float* __restrict__ bias,
        const float* __restrict__ res, size_t sR,
        void* __restrict__ out, int ldo, size_t sO) {
    __shared__ __bf16 As[3][128][32];
    __shared__ __bf16 Bs[3][128][32];

    const int t = threadIdx.x, w = t >> 6, l = t & 63;
    const int l15 = l & 15, lq = l >> 4;
    const int bz = blockIdx.z;

    const int gx = gridDim.x;
    int lin = blockIdx.y * gx + blockIdx.x;
    {
        const int nwg = gx * gridDim.y;
        const int qn = nwg >> 3, rn = nwg & 7;
        const int xcd = lin & 7, idx = lin >> 3;
        const int base = (xcd < rn) ? xcd*(qn+1) : rn*(qn+1) + (xcd-rn)*qn;
        lin = base + idx;
    }
    const int j0 = (lin % gx) * 128;
    const int i0 = (lin / gx) * 128;

    const __bf16* Ab = A + sA*bz;
    const __bf16* Bb = B + sB*bz;
    const int rowblk = (w & 1)*64;
    const int colblk = (w >> 1)*64;

    const int slot0 = w*64 + l;
    const int rowS0 = slot0 >> 2;
    const int rowS1 = rowS0 + 64;
    const int csS   = (((slot0 & 3) ^ ((rowS0 >> 1) & 3))) * 8;
    const int off0  = (w*64)*16;
    const int off1  = (256 + w*64)*16;

    f32x4 acc[4][4];
    #pragma unroll
    for (int mr = 0; mr < 4; ++mr)
        #pragma unroll
        for (int nr = 0; nr < 4; ++nr)
            #pragma unroll
            for (int r = 0; r < 4; ++r) acc[mr][nr][r] = 0.f;

    auto STAGE = [&](int kc, int bi) {
        char* Ad = (char*)As[bi];
        char* Bd = (char*)Bs[bi];
        gload16(Ab + (size_t)(i0 + rowS0)*lda + kc + csS, Ad + off0);
        gload16(Ab + (size_t)(i0 + rowS1)*lda + kc + csS, Ad + off1);
        gload16(Bb + (size_t)(j0 + rowS0)*ldb + kc + csS, Bd + off0);
        gload16(Bb + (size_t)(j0 + rowS1)*ldb + kc + csS, Bd + off1);
    };

    const int rsw = (l15 >> 1) & 3;
    const int koff = (lq ^ rsw) << 4;

    const int nch = Kdim >> 5;
    STAGE(0, 0);
    STAGE(32, 1);

    for (int cc = 0; cc < nch; ++cc) {
        if (cc < nch - 1) asm volatile("s_waitcnt vmcnt(4)\n\ts_barrier" ::: "memory");
        else              asm volatile("s_waitcnt vmcnt(0)\n\ts_barrier" ::: "memory");

        const char* Ac = (const char*)As[cc % 3];
        const char* Bc = (const char*)Bs[cc % 3];
        bf16x8 av[4], bv[4];
        #pragma unroll
        for (int mr = 0; mr < 4; ++mr)
            av[mr] = *(const bf16x8*)(Ac + (rowblk + mr*16 + l15)*64 + koff);
        #pragma unroll
        for (int nr = 0; nr < 4; ++nr)
            bv[nr] = *(const bf16x8*)(Bc + (colblk + nr*16 + l15)*64 + koff);
        if (cc + 2 < nch) STAGE((cc + 2)*32, (cc + 2) % 3);
        #pragma unroll
        for (int mr = 0; mr < 4; ++mr)
            #pragma unroll
            for (int nr = 0; nr < 4; ++nr)
                acc[mr][nr] = __builtin_amdgcn_mfma_f32_16x16x32_bf16(av[mr], bv[nr], acc[mr][nr], 0, 0, 0);
    }

    #pragma unroll
    for (int mr = 0; mr < 4; ++mr)
        #pragma unroll
        for (int nr = 0; nr < 4; ++nr) {
            int col = j0 + colblk + nr*16 + l15;
            #pragma unroll
            for (int r = 0; r < 4; ++r) {
                int lrow = rowblk + mr*16 + lq*4 + r;
                int gi = i0 + lrow;
                float v = acc[mr][nr][r];
                if constexpr (MODE == 1) {
                    v += bias[gi];
                    ((__bf16*)out)[sO*bz + (size_t)gi*ldo + col] = (__bf16)v;
                } else {
                    v += bias[gi] + res[sR*bz + (size_t)gi*ldo + col];
                    ((float*)out)[sO*bz + (size_t)gi*ldo + col] = v;
                }
            }
        }
}

// ---------------------------------------------------------------- 256x256 MFMA GEMM
// 512 thr / 8 waves (2M x 4N), wave tile 128x64 = 8x4 accs of 16x16x32, BK=32.
// 3-ring dynamic LDS (96KB), vmcnt(4)+barrier, gload16 + XOR source swizzle.
// MODE 0: +bias[col], bf16 out                 (QKV -> qkT)
// MODE 3: exp(acc*SCALE) -> bf16 P + rowpart   (S-GEMM)
// MODE 4: split-K=2 partial, raw bf16 out      (PV-GEMM; z = relbatch*2+kh)
#define LDSB (98304 + 4096)
template<int MODE>
__global__ __launch_bounds__(512) void mm256(
        const __bf16* __restrict__ A, int lda, size_t sA,
        const __bf16* __restrict__ B, int ldb, size_t sB,
        int Kdim,
        const float* __restrict__ bias,
        void* __restrict__ out, int ldo, size_t sO,
        float* __restrict__ rowpart) {
    extern __shared__ char smem[];
    char*  Abase = smem;             // 3 x 16KB  [256 rows][32 k] each
    char*  Bbase = smem + 49152;     // 3 x 16KB
    float* redp  = (float*)(smem + 98304);   // MODE3: [256][4]

    const int t = threadIdx.x, w = t >> 6, l = t & 63;
    const int l15 = l & 15, lq = l >> 4;
    const int bz = (MODE == 4) ? (blockIdx.z >> 1) : blockIdx.z;
    const int kh = (MODE == 4) ? (blockIdx.z & 1) : 0;
    const size_t kbase = (size_t)kh * Kdim;

    const int gx = gridDim.x;
    int lin = blockIdx.y * gx + blockIdx.x;
    {
        const int nwg = gx * gridDim.y;
        const int qn = nwg >> 3, rn = nwg & 7;
        const int xcd = lin & 7, idx = lin >> 3;
        const int base = (xcd < rn) ? xcd*(qn+1) : rn*(qn+1) + (xcd-rn)*qn;
        lin = base + idx;
    }
    const int j0 = (lin % gx) * 256;
    const int i0 = (lin / gx) * 256;

    const __bf16* Ab = A + sA*bz + kbase;
    const __bf16* Bb = B + sB*bz + kbase;
    const int wr = w & 1;            // M half (128 rows)
    const int wc = w >> 1;           // N quarter (64 cols)

    const int slot0 = w*64 + l;
    const int rowS0 = slot0 >> 2;
    const int rowS1 = rowS0 + 128;   // slot0+512
    const int csS   = (((slot0 & 3) ^ ((rowS0 >> 1) & 3))) * 8;
    const int off0  = (w*64)*16;
    const int off1  = (512 + w*64)*16;

    f32x4 acc[8][4];
    #pragma unroll
    for (int mr = 0; mr < 8; ++mr)
        #pragma unroll
        for (int nr = 0; nr < 4; ++nr)
            #pragma unroll
            for (int r = 0; r < 4; ++r) acc[mr][nr][r] = 0.f;

    auto STAGE = [&](int kc, int bi) {   // 4 vmem ops per thread
        char* Ad = Abase + bi*16384;
        char* Bd = Bbase + bi*16384;
        gload16(Ab + (size_t)(i0 + rowS0)*lda + kc + csS, Ad + off0);
        gload16(Ab + (size_t)(i0 + rowS1)*lda + kc + csS, Ad + off1);
        gload16(Bb + (size_t)(j0 + rowS0)*ldb + kc + csS, Bd + off0);
        gload16(Bb + (size_t)(j0 + rowS1)*ldb + kc + csS, Bd + off1);
    };

    const int rsw = (l15 >> 1) & 3;
    const int koff = (lq ^ rsw) << 4;

    const int nch = Kdim >> 5;
    STAGE(0, 0);
    STAGE(32, 1);

    for (int cc = 0; cc < nch; ++cc) {
        if (cc < nch - 1) asm volatile("s_waitcnt vmcnt(4)\n\ts_barrier" ::: "memory");
        else              asm volatile("s_waitcnt vmcnt(0)\n\ts_barrier" ::: "memory");

        const char* Ac = Abase + (cc % 3)*16384;
        const char* Bc = Bbase + (cc % 3)*16384;
        bf16x8 av[8], bv[4];
        #pragma unroll
        for (int mr = 0; mr < 8; ++mr)
            av[mr] = *(const bf16x8*)(Ac + (wr*128 + mr*16 + l15)*64 + koff);
        #pragma unroll
        for (int nr = 0; nr < 4; ++nr)
            bv[nr] = *(const bf16x8*)(Bc + (wc*64 + nr*16 + l15)*64 + koff);
        if (cc + 2 < nch) STAGE((cc + 2)*32, (cc + 2) % 3);
        #pragma unroll
        for (int mr = 0; mr < 8; ++mr)
            #pragma unroll
            for (int nr = 0; nr < 4; ++nr)
                acc[mr][nr] = __builtin_amdgcn_mfma_f32_16x16x32_bf16(av[mr], bv[nr], acc[mr][nr], 0, 0, 0);
    }

    if constexpr (MODE == 3) {
        const int jblk = j0 >> 8;
        float rpart[8][4];
        #pragma unroll
        for (int mr = 0; mr < 8; ++mr)
            #pragma unroll
            for (int r = 0; r < 4; ++r) rpart[mr][r] = 0.f;
        #pragma unroll
        for (int mr = 0; mr < 8; ++mr)
            #pragma unroll
            for (int nr = 0; nr < 4; ++nr) {
                int col = j0 + wc*64 + nr*16 + l15;
                #pragma unroll
                for (int r = 0; r < 4; ++r) {
                    int row = wr*128 + mr*16 + lq*4 + r;
                    float e = __expf(acc[mr][nr][r] * SCALE);
                    ((__bf16*)out)[sO*bz + (size_t)(i0 + row)*ldo + col] = (__bf16)e;
                    rpart[mr][r] += e;
                }
            }
        #pragma unroll
        for (int m = 1; m < 16; m <<= 1)
            #pragma unroll
            for (int mr = 0; mr < 8; ++mr)
                #pragma unroll
                for (int r = 0; r < 4; ++r)
                    rpart[mr][r] += __shfl_xor(rpart[mr][r], m);
        if (l15 == 0) {
            #pragma unroll
            for (int mr = 0; mr < 8; ++mr)
                #pragma unroll
                for (int r = 0; r < 4; ++r)
                    redp[(wr*128 + mr*16 + lq*4 + r)*4 + wc] = rpart[mr][r];
        }
        __syncthreads();
        if (t < 256)
            rowpart[(size_t)bz*131072 + (size_t)jblk*4096 + i0 + t] =
                redp[t*4+0] + redp[t*4+1] + redp[t*4+2] + redp[t*4+3];
        return;
    }

    // MODE 0 / MODE 4
    #pragma unroll
    for (int mr = 0; mr < 8; ++mr)
        #pragma unroll
        for (int nr = 0; nr < 4; ++nr) {
            int col = j0 + wc*64 + nr*16 + l15;
            #pragma unroll
            for (int r = 0; r < 4; ++r) {
                int lrow = wr*128 + mr*16 + lq*4 + r;
                if constexpr (MODE == 0) {
                    float v = acc[mr][nr][r] + bias[col];
                    ((__bf16*)out)[sO*bz + (size_t)(i0 + lrow)*ldo + col] = (__bf16)v;
                } else {  // MODE 4: raw partial, kh half
                    __bf16* po = (__bf16*)out + sO*bz + (size_t)kh*4096*ldo;
                    po[(size_t)(i0 + lrow)*ldo + col] = (__bf16)acc[mr][nr][r];
                }
            }
        }
}

// ---------------------------------------------------------------- PV split-K reduce
// OT[n][c] = (part0[n][c] + part1[n][c]) * (1/rowsum[n])
__global__ __launch_bounds__(256) void pv_reduce(const __bf16* __restrict__ part,
                                                 const float* __restrict__ rowpart,
                                                 __bf16* __restrict__ OT) {
    int b = blockIdx.y, r0 = blockIdx.x * 16;
    __shared__ float rs[16];
    int t = threadIdx.x;
    if (t < 16) {
        const float* rp = rowpart + (size_t)b*131072 + r0 + t;
        float s = 0.f;
        #pragma unroll
        for (int jb = 0; jb < 16; ++jb) s += rp[jb*4096];
        rs[t] = 1.0f / s;
    }
    __syncthreads();
    int row = r0 + (t >> 4), cseg = (t & 15) * 32;
    const __bf16* p0 = part + (size_t)b*4194304 + (size_t)row*512 + cseg;
    const __bf16* p1 = p0 + 2097152;
    __bf16* o = OT + (size_t)b*2097152 + (size_t)row*512 + cseg;
    float sc = rs[t >> 4];
    #pragma unroll
    for (int v8 = 0; v8 < 4; ++v8) {
        bf16x8 a = *(const bf16x8*)(p0 + v8*8);
        bf16x8 bb = *(const bf16x8*)(p1 + v8*8);
        bf16x8 r;
        #pragma unroll
        for (int e = 0; e < 8; ++e) r[e] = (__bf16)(((float)a[e] + (float)bb[e]) * sc);
        *(bf16x8*)(o + v8*8) = r;
    }
}

extern "C" void kernel_launch(void* const* d_in, const int* in_sizes, int n_in,
                              void* d_out, int out_size, void* d_ws, size_t ws_size,
                              hipStream_t stream) {
    const float* x      = (const float*)d_in[0];
    const float* gn_w   = (const float*)d_in[1];
    const float* gn_b   = (const float*)d_in[2];
    const float* qkv_w  = (const float*)d_in[3];
    const float* qkv_b  = (const float*)d_in[4];
    const float* proj_w = (const float*)d_in[5];
    const float* proj_b = (const float*)d_in[6];

    char* w8 = (char*)d_ws;
    __bf16* qkT  = (__bf16*)(w8);                 // 32 MB  [B][4096][1024]; per-batch slot reused for PV partials
    __bf16* Vbuf = (__bf16*)(w8 + 33554432);      // 16 MB  [B][512][4096]
    __bf16* OT   = (__bf16*)(w8 + 50331648);      // 16 MB  [B][4096][512]
    __bf16* wq   = (__bf16*)(w8 + 67108864);      // 1.5 MB [1536][512]
    __bf16* pw   = (__bf16*)(w8 + 68681728);      // 0.5 MB [512][512]
    float*  rowpart = (float*)(w8 + 69206016);    // 2 MB   [4][16][4096] (stride 131072)
    float*  part = (float*)(w8 + 71303168);       // 4 KB gn partials
    float*  st   = (float*)(w8 + 71307264);       // 256 B stats
    const size_t baseP = 71307520ULL;
    __bf16* hT   = (__bf16*)(w8 + baseP);         // 16 MB [B][4096][512] (dead after QKV)
    __bf16* P    = (__bf16*)(w8 + baseP);         // P chunks alias hT

    size_t avail = (ws_size > baseP) ? (ws_size - baseP) : 0;
    int cap = (int)(avail / 33554432ULL);
    if (cap < 1) cap = 1;
    if (cap > 4) cap = 4;

    hipFuncSetAttribute((const void*)mm256<0>,
                        hipFuncAttributeMaxDynamicSharedMemorySize, LDSB);
    hipFuncSetAttribute((const void*)mm256<3>,
                        hipFuncAttributeMaxDynamicSharedMemorySize, LDSB);
    hipFuncSetAttribute((const void*)mm256<4>,
                        hipFuncAttributeMaxDynamicSharedMemorySize, LDSB);

    wconv<<<768, 256, 0, stream>>>(qkv_w, wq, 1536*512);
    wconv<<<256, 256, 0, stream>>>(proj_w, pw, 512*512);
    gn_part<<<512, 256, 0, stream>>>(x, part);
    gn_fin<<<1, 64, 0, stream>>>(part, st);
    gn_apply_t<<<dim3(64, 8, 4), 256, 0, stream>>>(x, st, gn_w, gn_b, hT);

    // qkT[b][n][o] = sum_c hT[b][n][c]*qkv_w[o][c] + qkv_b[o], o in [0,1024)
    mm256<0><<<dim3(4, 16, 4), 512, LDSB, stream>>>(
        hT, 512, (size_t)4096*512, wq, 512, 0, 512,
        qkv_b, qkT, 1024, (size_t)4096*1024, nullptr);
    // V[b][o][n] = sum_c qkv_w[1024+o][c]*hT[b][n][c] + qkv_b[1024+o]
    mm128<1><<<dim3(32, 4, 4), 256, 0, stream>>>(
        wq + (size_t)1024*512, 512, 0, hT, 512, (size_t)4096*512, 512,
        qkv_b + 1024, nullptr, 0, Vbuf, 4096, (size_t)512*4096);

    for (int b0 = 0; b0 < 4; b0 += cap) {
        int c = (4 - b0 < cap) ? (4 - b0) : cap;
        // P[z][q][key] = exp(SCALE * sum_c Q[q][c]K[key][c]); rowpart written
        mm256<3><<<dim3(16, 16, c), 512, LDSB, stream>>>(
            qkT + (size_t)b0*4194304, 1024, (size_t)4096*1024,
            qkT + (size_t)b0*4194304 + 512, 1024, (size_t)4096*1024, 512,
            nullptr, P, 4096, (size_t)4096*4096,
            rowpart + (size_t)b0*131072);
        // PV split-K=2: raw bf16 partials into the (now dead) qkT slot of each batch
        mm256<4><<<dim3(2, 16, c*2), 512, LDSB, stream>>>(
            P, 4096, (size_t)4096*4096,
            Vbuf + (size_t)b0*2097152, 4096, (size_t)512*4096, 2048,
            nullptr, qkT + (size_t)b0*4194304, 512, (size_t)4194304,
            nullptr);
        // OT = (part0+part1) * 1/rowsum
        pv_reduce<<<dim3(256, c), 256, 0, stream>>>(
            qkT + (size_t)b0*4194304, rowpart + (size_t)b0*131072,
            OT + (size_t)b0*2097152);
    }

    // out[b][co][n] = x + sum_c proj_w[co][c]*OT[b][n][c] + proj_b[co]
    mm128<2><<<dim3(32, 4, 4), 256, 0, stream>>>(
        pw, 512, 0, OT, 512, (size_t)4096*512, 512,
        proj_b, x, (size_t)512*4096, (float*)d_out, 4096, (size_t)512*4096);
}